// Round 13
// baseline (446.875 us; speedup 1.0000x reference)
//
#include <hip/hip_runtime.h>
#include <hip/hip_bf16.h>
#include <math.h>

#define NN 20000
#define DD 64
#define HH 10
#define HDIM 640
#define NEG 0.2f
#define H1 1500
#define ASTRIDE 12   // a_src/a_dst row stride (floats): 48B, 16B-aligned
#define BKK 128      // gemm2 K-tile

typedef _Float16 half8 __attribute__((ext_vector_type(8)));
typedef _Float16 half4v __attribute__((ext_vector_type(4)));
typedef _Float16 half2v __attribute__((ext_vector_type(2)));
typedef float f32x4 __attribute__((ext_vector_type(4)));

// ---------------- both weight transposes in one launch ----------------
__global__ __launch_bounds__(256) void k_cvtB(const float* __restrict__ Wgcn,
                                              const float* __restrict__ Wg,
                                              _Float16* __restrict__ Wbt,
                                              _Float16* __restrict__ WgT)
{
    __shared__ float t[32][33];
    const int bx = blockIdx.x;
    int by = blockIdx.y;
    const float* W; _Float16* WT; int rows, cols;
    if (by < 20) { W = Wgcn; WT = Wbt; rows = HDIM; cols = HDIM; }
    else         { W = Wg;   WT = WgT; rows = DD;   cols = HDIM; by -= 20; }
    const int lx = threadIdx.x & 31, ly = threadIdx.x >> 5;
    #pragma unroll
    for (int i = ly; i < 32; i += 8)
        t[i][lx] = W[(size_t)(by * 32 + i) * cols + bx * 32 + lx];
    __syncthreads();
    #pragma unroll
    for (int j = ly; j < 32; j += 8)
        WT[(size_t)(bx * 32 + j) * rows + by * 32 + lx] = (_Float16)t[lx][j];
}

// ---------------- GEMM1 (MFMA fp16): xl = x @ W_gat, fused a_src/a_dst dots ----------------
__global__ __launch_bounds__(256) void k_gemm1(
    const float* __restrict__ x, const _Float16* __restrict__ WgT,
    const float* __restrict__ att_s, const float* __restrict__ att_d,
    _Float16* __restrict__ xl, float* __restrict__ a_src, float* __restrict__ a_dst)
{
    __shared__ _Float16 As[128][72];
    __shared__ _Float16 Bs[64][72];
    const int tid = threadIdx.x;
    const int m0 = blockIdx.x * 128;
    const int h  = blockIdx.y;
    const int n0 = h * 64;

    {
        const int row = tid >> 1, ch = (tid & 1) * 32;
        const int gr = m0 + row;
        if (gr < NN) {
            const float* xp = &x[(size_t)gr * DD + ch];
            #pragma unroll
            for (int i = 0; i < 8; ++i) {
                const float4 v = *(const float4*)&xp[i * 4];
                half4v o = {(_Float16)v.x, (_Float16)v.y, (_Float16)v.z, (_Float16)v.w};
                *(half4v*)&As[row][ch + i * 4] = o;
            }
        } else {
            const half8 z = {0, 0, 0, 0, 0, 0, 0, 0};
            #pragma unroll
            for (int i = 0; i < 4; ++i) *(half8*)&As[row][ch + i * 8] = z;
        }
    }
    {
        const int row = tid >> 2, part = (tid & 3) * 16;
        const _Float16* wp = &WgT[(size_t)(n0 + row) * DD + part];
        *(half8*)&Bs[row][part]     = *(const half8*)&wp[0];
        *(half8*)&Bs[row][part + 8] = *(const half8*)&wp[8];
    }
    __syncthreads();

    const int lane = tid & 63, wave = tid >> 6;
    const int l15 = lane & 15, quad = lane >> 4;
    f32x4 acc[2][4];
    #pragma unroll
    for (int r = 0; r < 2; ++r)
        #pragma unroll
        for (int c = 0; c < 4; ++c) acc[r][c] = (f32x4){0.f, 0.f, 0.f, 0.f};

    #pragma unroll
    for (int ks = 0; ks < 2; ++ks) {
        const half8 a0 = *(const half8*)&As[wave * 32 + l15][ks * 32 + quad * 8];
        const half8 a1 = *(const half8*)&As[wave * 32 + 16 + l15][ks * 32 + quad * 8];
        #pragma unroll
        for (int c = 0; c < 4; ++c) {
            const half8 b = *(const half8*)&Bs[c * 16 + l15][ks * 32 + quad * 8];
            acc[0][c] = __builtin_amdgcn_mfma_f32_16x16x32_f16(a0, b, acc[0][c], 0, 0, 0);
            acc[1][c] = __builtin_amdgcn_mfma_f32_16x16x32_f16(a1, b, acc[1][c], 0, 0, 0);
        }
    }

    float asv[4], adv[4];
    #pragma unroll
    for (int c = 0; c < 4; ++c) {
        asv[c] = att_s[h * DD + c * 16 + l15];
        adv[c] = att_d[h * DD + c * 16 + l15];
    }
    #pragma unroll
    for (int r = 0; r < 2; ++r) {
        float ps[4] = {0.f, 0.f, 0.f, 0.f}, pd[4] = {0.f, 0.f, 0.f, 0.f};
        #pragma unroll
        for (int c = 0; c < 4; ++c)
            #pragma unroll
            for (int g = 0; g < 4; ++g) {
                ps[g] = fmaf(acc[r][c][g], asv[c], ps[g]);
                pd[g] = fmaf(acc[r][c][g], adv[c], pd[g]);
            }
        #pragma unroll
        for (int m = 1; m <= 8; m <<= 1)
            #pragma unroll
            for (int g = 0; g < 4; ++g) {
                ps[g] += __shfl_xor(ps[g], m);
                pd[g] += __shfl_xor(pd[g], m);
            }
        #pragma unroll
        for (int c = 0; c < 4; ++c)
            #pragma unroll
            for (int g = 0; g < 4; ++g) {
                const int row = m0 + wave * 32 + r * 16 + quad * 4 + g;
                if (row < NN)
                    xl[(size_t)row * HDIM + n0 + c * 16 + l15] = (_Float16)acc[r][c][g];
            }
        if (l15 == 0)
            #pragma unroll
            for (int g = 0; g < 4; ++g) {
                const int row = m0 + wave * 32 + r * 16 + quad * 4 + g;
                if (row < NN) {
                    a_src[(size_t)row * ASTRIDE + h] = ps[g];
                    a_dst[(size_t)row * ASTRIDE + h] = pd[g];
                }
            }
    }
}

// ---------------- fused count + scan (ticket / last-block) ----------------
__global__ __launch_bounds__(1024) void k_count_scan(
    const int* __restrict__ ei, int E, int* __restrict__ cnt,
    int* __restrict__ rowptr, float* __restrict__ dinv, int* __restrict__ ticket)
{
    const int e = blockIdx.x * 1024 + threadIdx.x;
    if (e < E + NN) {
        const int d = (e < E) ? ei[E + e] : (e - E);
        atomicAdd(&cnt[d], 1);
    }
    __threadfence();
    __shared__ int lastf;
    if (threadIdx.x == 0)
        lastf = (atomicAdd(ticket, 1) == (int)gridDim.x - 1);
    __syncthreads();
    if (!lastf) return;
    __threadfence();

    __shared__ int sh[1024];
    const int t = threadIdx.x;
    const int CH = 20;
    const int base = t * CH;
    int loc[CH];
    int s = 0;
    #pragma unroll
    for (int i = 0; i < CH; ++i) {
        const int idx = base + i;
        const int c = (idx < NN) ? cnt[idx] : 0;
        loc[i] = s; s += c;
    }
    sh[t] = s; __syncthreads();
    for (int off = 1; off < 1024; off <<= 1) {
        const int v = (t >= off) ? sh[t - off] : 0;
        __syncthreads();
        sh[t] += v;
        __syncthreads();
    }
    const int prev = (t == 0) ? 0 : sh[t - 1];
    #pragma unroll
    for (int i = 0; i < CH; ++i) {
        const int idx = base + i;
        if (idx < NN) {
            rowptr[idx] = prev + loc[i];
            dinv[idx]   = rsqrtf((float)cnt[idx]);
        }
    }
    if (t == 1023) rowptr[NN] = sh[1023];
}

// ---------------- fill CSR + GCN norm + GAT edge weights ----------------
__global__ void k_fill(const int* __restrict__ ei, int E,
                       const int* __restrict__ rowptr,
                       int* __restrict__ cursor, int* __restrict__ csr,
                       const float* __restrict__ dinv, float* __restrict__ wn,
                       const float* __restrict__ aS, const float* __restrict__ aD,
                       float* __restrict__ wgat)
{
    const int e = blockIdx.x * blockDim.x + threadIdx.x;
    if (e >= E + NN) return;
    int s, d;
    if (e < E) { s = ei[e]; d = ei[E + e]; } else { s = d = e - E; }
    const int pos = atomicAdd(&cursor[d], 1);
    const int idx = rowptr[d] + pos;
    csr[idx] = s;
    wn[idx]  = dinv[s] * dinv[d];

    const f32x4 s0 = *(const f32x4*)&aS[(size_t)s * ASTRIDE];
    const f32x4 s1 = *(const f32x4*)&aS[(size_t)s * ASTRIDE + 4];
    const float2 s2 = *(const float2*)&aS[(size_t)s * ASTRIDE + 8];
    const f32x4 d0 = *(const f32x4*)&aD[(size_t)d * ASTRIDE];
    const f32x4 d1 = *(const f32x4*)&aD[(size_t)d * ASTRIDE + 4];
    const float2 d2 = *(const float2*)&aD[(size_t)d * ASTRIDE + 8];
    const float av[10] = {s0.x + d0.x, s0.y + d0.y, s0.z + d0.z, s0.w + d0.w,
                          s1.x + d1.x, s1.y + d1.y, s1.z + d1.z, s1.w + d1.w,
                          s2.x + d2.x, s2.y + d2.y};
    float* wp = &wgat[(size_t)idx * HH];
    #pragma unroll
    for (int h = 0; h < 10; ++h) {
        float a = av[h];
        a = (a >= 0.f) ? a : NEG * a;
        wp[h] = __expf(a);
    }
}

// ---------------- GAT gather: 2 waves per node (edge-split), LDS combine ----------------
__global__ __launch_bounds__(256) void k_gat_gather(
    const int* __restrict__ rowptr, const int* __restrict__ csr,
    const float* __restrict__ wgat, const _Float16* __restrict__ xl,
    const float* __restrict__ b_gat, _Float16* __restrict__ x1)
{
    __shared__ float lsh[2][720];   // 640 acc + 64 ws0 + 16 ws1
    const int wv = threadIdx.x >> 6, lane = threadIdx.x & 63;
    const int sub = wv >> 1, half = wv & 1;
    const int n = blockIdx.x * 2 + sub;
    const int c0 = lane * 8;
    const int h0 = lane >> 3;
    const bool dual = (lane < 16);
    const int c1 = 512 + lane * 8;
    const int h1 = 8 + (lane >> 3);

    float acc0[8], acc1[8], ws0 = 0.f, ws1 = 0.f;
    #pragma unroll
    for (int i = 0; i < 8; ++i) { acc0[i] = 0.f; acc1[i] = 0.f; }

    const int r0 = rowptr[n], r1 = rowptr[n + 1];
    const int mid = (r0 + r1 + 1) >> 1;
    const int j0 = half ? mid : r0;
    const int j1 = half ? r1 : mid;
    int j = j0;
    for (; j + 3 < j1; j += 4) {
        const int sA = csr[j], sB = csr[j + 1], sC = csr[j + 2], sD = csr[j + 3];
        const float wA0 = wgat[(size_t)(j + 0) * HH + h0];
        const float wB0 = wgat[(size_t)(j + 1) * HH + h0];
        const float wC0 = wgat[(size_t)(j + 2) * HH + h0];
        const float wD0 = wgat[(size_t)(j + 3) * HH + h0];
        ws0 += wA0 + wB0 + wC0 + wD0;
        const half8 vA0 = *(const half8*)&xl[(size_t)sA * HDIM + c0];
        const half8 vB0 = *(const half8*)&xl[(size_t)sB * HDIM + c0];
        const half8 vC0 = *(const half8*)&xl[(size_t)sC * HDIM + c0];
        const half8 vD0 = *(const half8*)&xl[(size_t)sD * HDIM + c0];
        #pragma unroll
        for (int i = 0; i < 8; ++i) {
            acc0[i] = fmaf(wA0, (float)vA0[i], acc0[i]);
            acc0[i] = fmaf(wB0, (float)vB0[i], acc0[i]);
            acc0[i] = fmaf(wC0, (float)vC0[i], acc0[i]);
            acc0[i] = fmaf(wD0, (float)vD0[i], acc0[i]);
        }
        if (dual) {
            const float wA1 = wgat[(size_t)(j + 0) * HH + h1];
            const float wB1 = wgat[(size_t)(j + 1) * HH + h1];
            const float wC1 = wgat[(size_t)(j + 2) * HH + h1];
            const float wD1 = wgat[(size_t)(j + 3) * HH + h1];
            ws1 += wA1 + wB1 + wC1 + wD1;
            const half8 vA1 = *(const half8*)&xl[(size_t)sA * HDIM + c1];
            const half8 vB1 = *(const half8*)&xl[(size_t)sB * HDIM + c1];
            const half8 vC1 = *(const half8*)&xl[(size_t)sC * HDIM + c1];
            const half8 vD1 = *(const half8*)&xl[(size_t)sD * HDIM + c1];
            #pragma unroll
            for (int i = 0; i < 8; ++i) {
                acc1[i] = fmaf(wA1, (float)vA1[i], acc1[i]);
                acc1[i] = fmaf(wB1, (float)vB1[i], acc1[i]);
                acc1[i] = fmaf(wC1, (float)vC1[i], acc1[i]);
                acc1[i] = fmaf(wD1, (float)vD1[i], acc1[i]);
            }
        }
    }
    for (; j < j1; ++j) {
        const int sA = csr[j];
        const float wA0 = wgat[(size_t)j * HH + h0];
        ws0 += wA0;
        const half8 vA0 = *(const half8*)&xl[(size_t)sA * HDIM + c0];
        #pragma unroll
        for (int i = 0; i < 8; ++i) acc0[i] = fmaf(wA0, (float)vA0[i], acc0[i]);
        if (dual) {
            const float wA1 = wgat[(size_t)j * HH + h1];
            ws1 += wA1;
            const half8 vA1 = *(const half8*)&xl[(size_t)sA * HDIM + c1];
            #pragma unroll
            for (int i = 0; i < 8; ++i) acc1[i] = fmaf(wA1, (float)vA1[i], acc1[i]);
        }
    }

    if (half) {
        float* p = lsh[sub];
        #pragma unroll
        for (int i = 0; i < 8; ++i) p[c0 + i] = acc0[i];
        if (dual) {
            #pragma unroll
            for (int i = 0; i < 8; ++i) p[c1 + i] = acc1[i];
        }
        p[640 + lane] = ws0;
        if (dual) p[704 + lane] = ws1;
    }
    __syncthreads();
    if (half) return;
    {
        const float* p = lsh[sub];
        #pragma unroll
        for (int i = 0; i < 8; ++i) acc0[i] += p[c0 + i];
        if (dual) {
            #pragma unroll
            for (int i = 0; i < 8; ++i) acc1[i] += p[c1 + i];
        }
        ws0 += p[640 + lane];
        if (dual) ws1 += p[704 + lane];
    }

    {
        const float rr = 1.f / (ws0 + 1e-16f);
        const float4 ba = *(const float4*)&b_gat[c0];
        const float4 bb = *(const float4*)&b_gat[c0 + 4];
        const float bv[8] = {ba.x, ba.y, ba.z, ba.w, bb.x, bb.y, bb.z, bb.w};
        half8 o;
        #pragma unroll
        for (int i = 0; i < 8; ++i) {
            const float v = fmaf(acc0[i], rr, bv[i]);
            o[i] = (_Float16)((v > 0.f) ? v : 0.f);
        }
        *(half8*)&x1[(size_t)n * HDIM + c0] = o;
    }
    if (dual) {
        const float rr = 1.f / (ws1 + 1e-16f);
        const float4 ba = *(const float4*)&b_gat[c1];
        const float4 bb = *(const float4*)&b_gat[c1 + 4];
        const float bv[8] = {ba.x, ba.y, ba.z, ba.w, bb.x, bb.y, bb.z, bb.w};
        half8 o;
        #pragma unroll
        for (int i = 0; i < 8; ++i) {
            const float v = fmaf(acc1[i], rr, bv[i]);
            o[i] = (_Float16)((v > 0.f) ? v : 0.f);
        }
        *(half8*)&x1[(size_t)n * HDIM + c1] = o;
    }
}

// ---------------- GCN gather: 2 waves per node (edge-split), LDS combine ----------------
__global__ __launch_bounds__(256) void k_gcn_gather(
    const int* __restrict__ rowptr, const int* __restrict__ csr,
    const float* __restrict__ wn, const _Float16* __restrict__ x1,
    _Float16* __restrict__ t)
{
    __shared__ float lsh[2][640];
    const int wv = threadIdx.x >> 6, lane = threadIdx.x & 63;
    const int sub = wv >> 1, half = wv & 1;
    const int n = blockIdx.x * 2 + sub;
    const int c0 = lane * 8;
    const bool dual = (lane < 16);
    const int c1 = 512 + lane * 8;

    float acc0[8], acc1[8];
    #pragma unroll
    for (int i = 0; i < 8; ++i) { acc0[i] = 0.f; acc1[i] = 0.f; }

    const int r0 = rowptr[n], r1 = rowptr[n + 1];
    const int mid = (r0 + r1 + 1) >> 1;
    const int j0 = half ? mid : r0;
    const int j1 = half ? r1 : mid;
    int j = j0;
    for (; j + 3 < j1; j += 4) {
        const int sA = csr[j], sB = csr[j + 1], sC = csr[j + 2], sD = csr[j + 3];
        const float wA = wn[j], wB = wn[j + 1], wC = wn[j + 2], wD = wn[j + 3];
        const half8 vA0 = *(const half8*)&x1[(size_t)sA * HDIM + c0];
        const half8 vB0 = *(const half8*)&x1[(size_t)sB * HDIM + c0];
        const half8 vC0 = *(const half8*)&x1[(size_t)sC * HDIM + c0];
        const half8 vD0 = *(const half8*)&x1[(size_t)sD * HDIM + c0];
        #pragma unroll
        for (int i = 0; i < 8; ++i) {
            acc0[i] = fmaf(wA, (float)vA0[i], acc0[i]);
            acc0[i] = fmaf(wB, (float)vB0[i], acc0[i]);
            acc0[i] = fmaf(wC, (float)vC0[i], acc0[i]);
            acc0[i] = fmaf(wD, (float)vD0[i], acc0[i]);
        }
        if (dual) {
            const half8 vA1 = *(const half8*)&x1[(size_t)sA * HDIM + c1];
            const half8 vB1 = *(const half8*)&x1[(size_t)sB * HDIM + c1];
            const half8 vC1 = *(const half8*)&x1[(size_t)sC * HDIM + c1];
            const half8 vD1 = *(const half8*)&x1[(size_t)sD * HDIM + c1];
            #pragma unroll
            for (int i = 0; i < 8; ++i) {
                acc1[i] = fmaf(wA, (float)vA1[i], acc1[i]);
                acc1[i] = fmaf(wB, (float)vB1[i], acc1[i]);
                acc1[i] = fmaf(wC, (float)vC1[i], acc1[i]);
                acc1[i] = fmaf(wD, (float)vD1[i], acc1[i]);
            }
        }
    }
    for (; j < j1; ++j) {
        const int sA = csr[j];
        const float wA = wn[j];
        const half8 vA0 = *(const half8*)&x1[(size_t)sA * HDIM + c0];
        #pragma unroll
        for (int i = 0; i < 8; ++i) acc0[i] = fmaf(wA, (float)vA0[i], acc0[i]);
        if (dual) {
            const half8 vA1 = *(const half8*)&x1[(size_t)sA * HDIM + c1];
            #pragma unroll
            for (int i = 0; i < 8; ++i) acc1[i] = fmaf(wA, (float)vA1[i], acc1[i]);
        }
    }

    if (half) {
        float* p = lsh[sub];
        #pragma unroll
        for (int i = 0; i < 8; ++i) p[c0 + i] = acc0[i];
        if (dual) {
            #pragma unroll
            for (int i = 0; i < 8; ++i) p[c1 + i] = acc1[i];
        }
    }
    __syncthreads();
    if (half) return;
    {
        const float* p = lsh[sub];
        #pragma unroll
        for (int i = 0; i < 8; ++i) acc0[i] += p[c0 + i];
        if (dual) {
            #pragma unroll
            for (int i = 0; i < 8; ++i) acc1[i] += p[c1 + i];
        }
    }

    {
        half8 o;
        #pragma unroll
        for (int i = 0; i < 8; ++i) o[i] = (_Float16)acc0[i];
        *(half8*)&t[(size_t)n * HDIM + c0] = o;
    }
    if (dual) {
        half8 o;
        #pragma unroll
        for (int i = 0; i < 8; ++i) o[i] = (_Float16)acc1[i];
        *(half8*)&t[(size_t)n * HDIM + c1] = o;
    }
}

// ---------------- GEMM2 (m97-style) + fused bias/relu/pool ----------------
__global__ __launch_bounds__(256) void k_gemm2(const _Float16* __restrict__ X,
                                               const _Float16* __restrict__ Wbt,
                                               const float* __restrict__ b_gcn,
                                               float* __restrict__ pmax,
                                               float* __restrict__ psum)
{
    __shared__ _Float16 Bs[128 * BKK];
    const int tid = threadIdx.x;
    const int lane = tid & 63, wave = tid >> 6;
    const int l15 = lane & 15, quad = lane >> 4;
    const int m0 = blockIdx.x * 128 + wave * 32;
    const int n0 = blockIdx.y * 128;
    const int l7 = l15 & 7;

    f32x4 acc[2][8];
    #pragma unroll
    for (int r = 0; r < 2; ++r)
        #pragma unroll
        for (int c = 0; c < 8; ++c) acc[r][c] = (f32x4){0.f, 0.f, 0.f, 0.f};

    const int jrow = lane >> 4;
    const int jchunk = lane & 15;

    const _Float16* a0p = &X[(size_t)(m0 + l15) * HDIM + quad * 8];
    const _Float16* a1p = a0p + (size_t)16 * HDIM;

    for (int kb = 0; kb < HDIM; kb += BKK) {
        #pragma unroll
        for (int i = 0; i < 8; ++i) {
            const int r = (wave * 8 + i) * 4 + jrow;
            const int ck = jchunk ^ (r & 7);
            const _Float16* src = &Wbt[(size_t)(n0 + r) * HDIM + kb + ck * 8];
            __builtin_amdgcn_global_load_lds(
                (const __attribute__((address_space(1))) void*)src,
                (__attribute__((address_space(3))) void*)&Bs[(size_t)(wave * 8 + i) * 512],
                16, 0, 0);
        }
        half8 a0[4], a1[4];
        #pragma unroll
        for (int ks = 0; ks < 4; ++ks) {
            a0[ks] = *(const half8*)(a0p + kb + ks * 32);
            a1[ks] = *(const half8*)(a1p + kb + ks * 32);
        }
        __syncthreads();
        #pragma unroll
        for (int ks = 0; ks < 4; ++ks) {
            #pragma unroll
            for (int c = 0; c < 8; ++c) {
                const int br = c * 16 + l15;
                const int ck = (4 * ks + quad) ^ l7;
                const half8 b = *(const half8*)&Bs[(size_t)br * BKK + ck * 8];
                acc[0][c] = __builtin_amdgcn_mfma_f32_16x16x32_f16(a0[ks], b, acc[0][c], 0, 0, 0);
                acc[1][c] = __builtin_amdgcn_mfma_f32_16x16x32_f16(a1[ks], b, acc[1][c], 0, 0, 0);
            }
        }
        __syncthreads();
    }

    float lmax[8], lsum[8];
    #pragma unroll
    for (int c = 0; c < 8; ++c) { lmax[c] = 0.f; lsum[c] = 0.f; }
    #pragma unroll
    for (int c = 0; c < 8; ++c) {
        const float bb = b_gcn[n0 + c * 16 + l15];
        #pragma unroll
        for (int r = 0; r < 2; ++r)
            #pragma unroll
            for (int g = 0; g < 4; ++g) {
                const int row = m0 + r * 16 + quad * 4 + g;
                if (row < NN) {
                    float v = acc[r][c][g] + bb;
                    v = (v > 0.f) ? v : 0.f;
                    lmax[c] = fmaxf(lmax[c], v);
                    lsum[c] += v;
                }
            }
    }
    float* redm = (float*)Bs;
    float* reds = redm + 128;
    if (tid < 128) { redm[tid] = 0.f; reds[tid] = 0.f; }
    __syncthreads();
    #pragma unroll
    for (int c = 0; c < 8; ++c) {
        const int col = c * 16 + l15;
        atomicMax((int*)&redm[col], __float_as_int(lmax[c]));
        atomicAdd(&reds[col], lsum[c]);
    }
    __syncthreads();
    if (tid < 128) {
        atomicMax((int*)&pmax[n0 + tid], __float_as_int(redm[tid]));
        atomicAdd(&psum[n0 + tid], reds[tid]);
    }
}

// ---------------- fused MLP (layer1 split-K + last-block layer2) ----------------
__global__ __launch_bounds__(256) void k_mlp(const float* __restrict__ pmax,
                                             const float* __restrict__ psum,
                                             const float* __restrict__ W1,
                                             const float* __restrict__ b1,
                                             const float* __restrict__ W2,
                                             const float* __restrict__ b2,
                                             float* __restrict__ hacc,
                                             int* __restrict__ ticket,
                                             float* __restrict__ out)
{
    __shared__ float pl[80];
    __shared__ int lastf;
    const int t = threadIdx.x;
    const int i0 = blockIdx.y * 80;
    if (t < 80) {
        const int i = i0 + t;
        pl[t] = (i < HDIM) ? pmax[i] : psum[i - HDIM] * (1.0f / NN);
    }
    __syncthreads();
    const int j = blockIdx.x * 256 + t;
    if (j < H1) {
        float acc = 0.f;
        #pragma unroll 8
        for (int i = 0; i < 80; ++i)
            acc = fmaf(pl[i], W1[(size_t)(i0 + i) * H1 + j], acc);
        atomicAdd(&hacc[j], acc);
    }
    __threadfence();
    if (t == 0)
        lastf = (atomicAdd(ticket, 1) == (int)(gridDim.x * gridDim.y) - 1);
    __syncthreads();
    if (!lastf) return;
    __threadfence();

    __shared__ float hsh[H1];
    __shared__ float red[256];
    for (int i = t; i < H1; i += 256) {
        const float v = hacc[i] + b1[i];
        hsh[i] = (v > 0.f) ? v : 0.f;
    }
    __syncthreads();
    float acc[10];
    #pragma unroll
    for (int k = 0; k < 10; ++k) acc[k] = 0.f;
    for (int i = t; i < H1; i += 256) {
        const float h = hsh[i];
        #pragma unroll
        for (int k = 0; k < 10; ++k) acc[k] = fmaf(h, W2[i * 10 + k], acc[k]);
    }
    for (int k = 0; k < 10; ++k) {
        red[t] = acc[k]; __syncthreads();
        for (int s2 = 128; s2 > 0; s2 >>= 1) {
            if (t < s2) red[t] += red[t + s2];
            __syncthreads();
        }
        if (t == 0) out[k] = red[0] + b2[k];
        __syncthreads();
    }
}

// ---------------- launch ----------------
extern "C" void kernel_launch(void* const* d_in, const int* in_sizes, int n_in,
                              void* d_out, int out_size, void* d_ws, size_t ws_size,
                              hipStream_t stream)
{
    const float* x     = (const float*)d_in[0];
    const float* Wg    = (const float*)d_in[1];
    const float* att_s = (const float*)d_in[2];
    const float* att_d = (const float*)d_in[3];
    const float* b_gat = (const float*)d_in[4];
    const float* Wgcn  = (const float*)d_in[5];
    const float* b_gcn = (const float*)d_in[6];
    const float* W1    = (const float*)d_in[7];
    const float* b1    = (const float*)d_in[8];
    const float* W2    = (const float*)d_in[9];
    const float* b2    = (const float*)d_in[10];
    const int*   ei    = (const int*)d_in[11];
    const int E = in_sizes[11] / 2;
    const int EP = E + NN;
    float* out = (float*)d_out;

    char* wsp = (char*)d_ws;
    size_t off = 0;
    auto alc = [&](size_t b) { void* p = wsp + off; off += (b + 255) & ~(size_t)255; return p; };
    _Float16* bufA = (_Float16*)alc((size_t)NN * HDIM * 2);  // xl, later t
    _Float16* bufB = (_Float16*)alc((size_t)NN * HDIM * 2);  // x1
    float* aS     = (float*)alc((size_t)NN * ASTRIDE * 4);
    float* aD     = (float*)alc((size_t)NN * ASTRIDE * 4);
    int*   rowptr = (int*)alc((size_t)(NN + 1) * 4);
    int*   csr    = (int*)alc((size_t)EP * 4);
    float* dinv   = (float*)alc((size_t)NN * 4);
    float* wn     = (float*)alc((size_t)EP * 4);
    float* wgat   = (float*)alc((size_t)EP * HH * 4);        // [edge][head]
    _Float16* Wbt = (_Float16*)alc((size_t)HDIM * HDIM * 2); // W_gcn^T fp16
    _Float16* WgT = (_Float16*)alc((size_t)HDIM * DD * 2);   // W_gat^T fp16 [640][64]
    // zero-initialized region (single memset): cnt | cursor | pmax | psum | hacc | tickets
    const size_t zoff = off;
    int*   cnt    = (int*)alc((size_t)NN * 4);
    int*   cursor = (int*)alc((size_t)NN * 4);
    float* pmax   = (float*)alc((size_t)HDIM * 4);
    float* psum   = (float*)alc((size_t)HDIM * 4);
    float* hacc   = (float*)alc((size_t)H1 * 4);
    int*   tks    = (int*)alc(2 * 4);
    const size_t zsize = off - zoff;

    hipMemsetAsync(cnt, 0, zsize, stream);

    dim3 gw(HDIM / 32, HDIM / 32 + DD / 32);
    k_cvtB<<<gw, 256, 0, stream>>>(Wgcn, Wg, Wbt, WgT);
    dim3 g1((NN + 127) / 128, HH);
    k_gemm1<<<g1, 256, 0, stream>>>(x, WgT, att_s, att_d, bufA, aS, aD);
    k_count_scan<<<(EP + 1023) / 1024, 1024, 0, stream>>>(ei, E, cnt, rowptr, dinv, tks);
    k_fill<<<(EP + 255) / 256, 256, 0, stream>>>(ei, E, rowptr, cursor, csr,
                                                 dinv, wn, aS, aD, wgat);
    k_gat_gather<<<NN / 2, 256, 0, stream>>>(rowptr, csr, wgat, bufA, b_gat, bufB);
    k_gcn_gather<<<NN / 2, 256, 0, stream>>>(rowptr, csr, wn, bufB, bufA);
    dim3 g2((NN + 127) / 128, HDIM / 128);
    k_gemm2<<<g2, 256, 0, stream>>>(bufA, Wbt, b_gcn, pmax, psum);
    dim3 gm1(6, 16);
    k_mlp<<<gm1, 256, 0, stream>>>(pmax, psum, W1, b1, W2, b2, hacc, tks + 1, out);
}

// Round 14
// 377.846 us; speedup vs baseline: 1.1827x; 1.1827x over previous
//
#include <hip/hip_runtime.h>
#include <hip/hip_bf16.h>
#include <math.h>

#define NN 20000
#define DD 64
#define HH 10
#define HDIM 640
#define NEG 0.2f
#define H1 1500
#define ASTRIDE 12   // a_src/a_dst row stride (floats): 48B, 16B-aligned
#define BKK 128      // gemm2 K-tile

typedef _Float16 half8 __attribute__((ext_vector_type(8)));
typedef _Float16 half4v __attribute__((ext_vector_type(4)));
typedef _Float16 half2v __attribute__((ext_vector_type(2)));
typedef float f32x4 __attribute__((ext_vector_type(4)));

// ---------------- both weight transposes in one launch ----------------
__global__ __launch_bounds__(256) void k_cvtB(const float* __restrict__ Wgcn,
                                              const float* __restrict__ Wg,
                                              _Float16* __restrict__ Wbt,
                                              _Float16* __restrict__ WgT)
{
    __shared__ float t[32][33];
    const int bx = blockIdx.x;
    int by = blockIdx.y;
    const float* W; _Float16* WT; int rows, cols;
    if (by < 20) { W = Wgcn; WT = Wbt; rows = HDIM; cols = HDIM; }
    else         { W = Wg;   WT = WgT; rows = DD;   cols = HDIM; by -= 20; }
    const int lx = threadIdx.x & 31, ly = threadIdx.x >> 5;
    #pragma unroll
    for (int i = ly; i < 32; i += 8)
        t[i][lx] = W[(size_t)(by * 32 + i) * cols + bx * 32 + lx];
    __syncthreads();
    #pragma unroll
    for (int j = ly; j < 32; j += 8)
        WT[(size_t)(bx * 32 + j) * rows + by * 32 + lx] = (_Float16)t[lx][j];
}

// ---------------- GEMM1 (MFMA fp16): xl = x @ W_gat, fused a_src/a_dst dots ----------------
__global__ __launch_bounds__(256) void k_gemm1(
    const float* __restrict__ x, const _Float16* __restrict__ WgT,
    const float* __restrict__ att_s, const float* __restrict__ att_d,
    _Float16* __restrict__ xl, float* __restrict__ a_src, float* __restrict__ a_dst)
{
    __shared__ _Float16 As[128][72];
    __shared__ _Float16 Bs[64][72];
    const int tid = threadIdx.x;
    const int m0 = blockIdx.x * 128;
    const int h  = blockIdx.y;
    const int n0 = h * 64;

    {
        const int row = tid >> 1, ch = (tid & 1) * 32;
        const int gr = m0 + row;
        if (gr < NN) {
            const float* xp = &x[(size_t)gr * DD + ch];
            #pragma unroll
            for (int i = 0; i < 8; ++i) {
                const float4 v = *(const float4*)&xp[i * 4];
                half4v o = {(_Float16)v.x, (_Float16)v.y, (_Float16)v.z, (_Float16)v.w};
                *(half4v*)&As[row][ch + i * 4] = o;
            }
        } else {
            const half8 z = {0, 0, 0, 0, 0, 0, 0, 0};
            #pragma unroll
            for (int i = 0; i < 4; ++i) *(half8*)&As[row][ch + i * 8] = z;
        }
    }
    {
        const int row = tid >> 2, part = (tid & 3) * 16;
        const _Float16* wp = &WgT[(size_t)(n0 + row) * DD + part];
        *(half8*)&Bs[row][part]     = *(const half8*)&wp[0];
        *(half8*)&Bs[row][part + 8] = *(const half8*)&wp[8];
    }
    __syncthreads();

    const int lane = tid & 63, wave = tid >> 6;
    const int l15 = lane & 15, quad = lane >> 4;
    f32x4 acc[2][4];
    #pragma unroll
    for (int r = 0; r < 2; ++r)
        #pragma unroll
        for (int c = 0; c < 4; ++c) acc[r][c] = (f32x4){0.f, 0.f, 0.f, 0.f};

    #pragma unroll
    for (int ks = 0; ks < 2; ++ks) {
        const half8 a0 = *(const half8*)&As[wave * 32 + l15][ks * 32 + quad * 8];
        const half8 a1 = *(const half8*)&As[wave * 32 + 16 + l15][ks * 32 + quad * 8];
        #pragma unroll
        for (int c = 0; c < 4; ++c) {
            const half8 b = *(const half8*)&Bs[c * 16 + l15][ks * 32 + quad * 8];
            acc[0][c] = __builtin_amdgcn_mfma_f32_16x16x32_f16(a0, b, acc[0][c], 0, 0, 0);
            acc[1][c] = __builtin_amdgcn_mfma_f32_16x16x32_f16(a1, b, acc[1][c], 0, 0, 0);
        }
    }

    float asv[4], adv[4];
    #pragma unroll
    for (int c = 0; c < 4; ++c) {
        asv[c] = att_s[h * DD + c * 16 + l15];
        adv[c] = att_d[h * DD + c * 16 + l15];
    }
    #pragma unroll
    for (int r = 0; r < 2; ++r) {
        float ps[4] = {0.f, 0.f, 0.f, 0.f}, pd[4] = {0.f, 0.f, 0.f, 0.f};
        #pragma unroll
        for (int c = 0; c < 4; ++c)
            #pragma unroll
            for (int g = 0; g < 4; ++g) {
                ps[g] = fmaf(acc[r][c][g], asv[c], ps[g]);
                pd[g] = fmaf(acc[r][c][g], adv[c], pd[g]);
            }
        #pragma unroll
        for (int m = 1; m <= 8; m <<= 1)
            #pragma unroll
            for (int g = 0; g < 4; ++g) {
                ps[g] += __shfl_xor(ps[g], m);
                pd[g] += __shfl_xor(pd[g], m);
            }
        #pragma unroll
        for (int c = 0; c < 4; ++c)
            #pragma unroll
            for (int g = 0; g < 4; ++g) {
                const int row = m0 + wave * 32 + r * 16 + quad * 4 + g;
                if (row < NN)
                    xl[(size_t)row * HDIM + n0 + c * 16 + l15] = (_Float16)acc[r][c][g];
            }
        if (l15 == 0)
            #pragma unroll
            for (int g = 0; g < 4; ++g) {
                const int row = m0 + wave * 32 + r * 16 + quad * 4 + g;
                if (row < NN) {
                    a_src[(size_t)row * ASTRIDE + h] = ps[g];
                    a_dst[(size_t)row * ASTRIDE + h] = pd[g];
                }
            }
    }
}

// ---------------- CSR build (separate count + scan: ticket fusion was 120us, reverted) ----------------
__global__ void k_count(const int* __restrict__ ei, int E, int* __restrict__ cnt)
{
    const int e = blockIdx.x * blockDim.x + threadIdx.x;
    if (e >= E + NN) return;
    const int d = (e < E) ? ei[E + e] : (e - E);
    atomicAdd(&cnt[d], 1);
}

__global__ __launch_bounds__(1024) void k_scan(const int* __restrict__ cnt,
                                               int* __restrict__ rowptr,
                                               float* __restrict__ dinv)
{
    __shared__ int sh[1024];
    const int t = threadIdx.x;
    const int CH = 20;
    const int base = t * CH;
    int loc[CH];
    int s = 0;
    #pragma unroll
    for (int i = 0; i < CH; ++i) {
        const int idx = base + i;
        const int c = (idx < NN) ? cnt[idx] : 0;
        loc[i] = s; s += c;
    }
    sh[t] = s; __syncthreads();
    for (int off = 1; off < 1024; off <<= 1) {
        const int v = (t >= off) ? sh[t - off] : 0;
        __syncthreads();
        sh[t] += v;
        __syncthreads();
    }
    const int prev = (t == 0) ? 0 : sh[t - 1];
    #pragma unroll
    for (int i = 0; i < CH; ++i) {
        const int idx = base + i;
        if (idx < NN) {
            rowptr[idx] = prev + loc[i];
            dinv[idx]   = rsqrtf((float)cnt[idx]);
        }
    }
    if (t == 1023) rowptr[NN] = sh[1023];
}

// ---------------- fill CSR + GCN norm + GAT edge weights ----------------
__global__ void k_fill(const int* __restrict__ ei, int E,
                       const int* __restrict__ rowptr,
                       int* __restrict__ cursor, int* __restrict__ csr,
                       const float* __restrict__ dinv, float* __restrict__ wn,
                       const float* __restrict__ aS, const float* __restrict__ aD,
                       float* __restrict__ wgat)
{
    const int e = blockIdx.x * blockDim.x + threadIdx.x;
    if (e >= E + NN) return;
    int s, d;
    if (e < E) { s = ei[e]; d = ei[E + e]; } else { s = d = e - E; }
    const int pos = atomicAdd(&cursor[d], 1);
    const int idx = rowptr[d] + pos;
    csr[idx] = s;
    wn[idx]  = dinv[s] * dinv[d];

    const f32x4 s0 = *(const f32x4*)&aS[(size_t)s * ASTRIDE];
    const f32x4 s1 = *(const f32x4*)&aS[(size_t)s * ASTRIDE + 4];
    const float2 s2 = *(const float2*)&aS[(size_t)s * ASTRIDE + 8];
    const f32x4 d0 = *(const f32x4*)&aD[(size_t)d * ASTRIDE];
    const f32x4 d1 = *(const f32x4*)&aD[(size_t)d * ASTRIDE + 4];
    const float2 d2 = *(const float2*)&aD[(size_t)d * ASTRIDE + 8];
    const float av[10] = {s0.x + d0.x, s0.y + d0.y, s0.z + d0.z, s0.w + d0.w,
                          s1.x + d1.x, s1.y + d1.y, s1.z + d1.z, s1.w + d1.w,
                          s2.x + d2.x, s2.y + d2.y};
    float* wp = &wgat[(size_t)idx * HH];
    #pragma unroll
    for (int h = 0; h < 10; ++h) {
        float a = av[h];
        a = (a >= 0.f) ? a : NEG * a;
        wp[h] = __expf(a);
    }
}

// ---------------- GAT gather: 2 waves per node (edge-split), LDS combine ----------------
__global__ __launch_bounds__(256) void k_gat_gather(
    const int* __restrict__ rowptr, const int* __restrict__ csr,
    const float* __restrict__ wgat, const _Float16* __restrict__ xl,
    const float* __restrict__ b_gat, _Float16* __restrict__ x1)
{
    __shared__ float lsh[2][720];   // 640 acc + 64 ws0 + 16 ws1
    const int wv = threadIdx.x >> 6, lane = threadIdx.x & 63;
    const int sub = wv >> 1, half = wv & 1;
    const int n = blockIdx.x * 2 + sub;
    const int c0 = lane * 8;
    const int h0 = lane >> 3;
    const bool dual = (lane < 16);
    const int c1 = 512 + lane * 8;
    const int h1 = 8 + (lane >> 3);

    float acc0[8], acc1[8], ws0 = 0.f, ws1 = 0.f;
    #pragma unroll
    for (int i = 0; i < 8; ++i) { acc0[i] = 0.f; acc1[i] = 0.f; }

    const int r0 = rowptr[n], r1 = rowptr[n + 1];
    const int mid = (r0 + r1 + 1) >> 1;
    const int j0 = half ? mid : r0;
    const int j1 = half ? r1 : mid;
    int j = j0;
    for (; j + 3 < j1; j += 4) {
        const int sA = csr[j], sB = csr[j + 1], sC = csr[j + 2], sD = csr[j + 3];
        const float wA0 = wgat[(size_t)(j + 0) * HH + h0];
        const float wB0 = wgat[(size_t)(j + 1) * HH + h0];
        const float wC0 = wgat[(size_t)(j + 2) * HH + h0];
        const float wD0 = wgat[(size_t)(j + 3) * HH + h0];
        ws0 += wA0 + wB0 + wC0 + wD0;
        const half8 vA0 = *(const half8*)&xl[(size_t)sA * HDIM + c0];
        const half8 vB0 = *(const half8*)&xl[(size_t)sB * HDIM + c0];
        const half8 vC0 = *(const half8*)&xl[(size_t)sC * HDIM + c0];
        const half8 vD0 = *(const half8*)&xl[(size_t)sD * HDIM + c0];
        #pragma unroll
        for (int i = 0; i < 8; ++i) {
            acc0[i] = fmaf(wA0, (float)vA0[i], acc0[i]);
            acc0[i] = fmaf(wB0, (float)vB0[i], acc0[i]);
            acc0[i] = fmaf(wC0, (float)vC0[i], acc0[i]);
            acc0[i] = fmaf(wD0, (float)vD0[i], acc0[i]);
        }
        if (dual) {
            const float wA1 = wgat[(size_t)(j + 0) * HH + h1];
            const float wB1 = wgat[(size_t)(j + 1) * HH + h1];
            const float wC1 = wgat[(size_t)(j + 2) * HH + h1];
            const float wD1 = wgat[(size_t)(j + 3) * HH + h1];
            ws1 += wA1 + wB1 + wC1 + wD1;
            const half8 vA1 = *(const half8*)&xl[(size_t)sA * HDIM + c1];
            const half8 vB1 = *(const half8*)&xl[(size_t)sB * HDIM + c1];
            const half8 vC1 = *(const half8*)&xl[(size_t)sC * HDIM + c1];
            const half8 vD1 = *(const half8*)&xl[(size_t)sD * HDIM + c1];
            #pragma unroll
            for (int i = 0; i < 8; ++i) {
                acc1[i] = fmaf(wA1, (float)vA1[i], acc1[i]);
                acc1[i] = fmaf(wB1, (float)vB1[i], acc1[i]);
                acc1[i] = fmaf(wC1, (float)vC1[i], acc1[i]);
                acc1[i] = fmaf(wD1, (float)vD1[i], acc1[i]);
            }
        }
    }
    for (; j < j1; ++j) {
        const int sA = csr[j];
        const float wA0 = wgat[(size_t)j * HH + h0];
        ws0 += wA0;
        const half8 vA0 = *(const half8*)&xl[(size_t)sA * HDIM + c0];
        #pragma unroll
        for (int i = 0; i < 8; ++i) acc0[i] = fmaf(wA0, (float)vA0[i], acc0[i]);
        if (dual) {
            const float wA1 = wgat[(size_t)j * HH + h1];
            ws1 += wA1;
            const half8 vA1 = *(const half8*)&xl[(size_t)sA * HDIM + c1];
            #pragma unroll
            for (int i = 0; i < 8; ++i) acc1[i] = fmaf(wA1, (float)vA1[i], acc1[i]);
        }
    }

    if (half) {
        float* p = lsh[sub];
        #pragma unroll
        for (int i = 0; i < 8; ++i) p[c0 + i] = acc0[i];
        if (dual) {
            #pragma unroll
            for (int i = 0; i < 8; ++i) p[c1 + i] = acc1[i];
        }
        p[640 + lane] = ws0;
        if (dual) p[704 + lane] = ws1;
    }
    __syncthreads();
    if (half) return;
    {
        const float* p = lsh[sub];
        #pragma unroll
        for (int i = 0; i < 8; ++i) acc0[i] += p[c0 + i];
        if (dual) {
            #pragma unroll
            for (int i = 0; i < 8; ++i) acc1[i] += p[c1 + i];
        }
        ws0 += p[640 + lane];
        if (dual) ws1 += p[704 + lane];
    }

    {
        const float rr = 1.f / (ws0 + 1e-16f);
        const float4 ba = *(const float4*)&b_gat[c0];
        const float4 bb = *(const float4*)&b_gat[c0 + 4];
        const float bv[8] = {ba.x, ba.y, ba.z, ba.w, bb.x, bb.y, bb.z, bb.w};
        half8 o;
        #pragma unroll
        for (int i = 0; i < 8; ++i) {
            const float v = fmaf(acc0[i], rr, bv[i]);
            o[i] = (_Float16)((v > 0.f) ? v : 0.f);
        }
        *(half8*)&x1[(size_t)n * HDIM + c0] = o;
    }
    if (dual) {
        const float rr = 1.f / (ws1 + 1e-16f);
        const float4 ba = *(const float4*)&b_gat[c1];
        const float4 bb = *(const float4*)&b_gat[c1 + 4];
        const float bv[8] = {ba.x, ba.y, ba.z, ba.w, bb.x, bb.y, bb.z, bb.w};
        half8 o;
        #pragma unroll
        for (int i = 0; i < 8; ++i) {
            const float v = fmaf(acc1[i], rr, bv[i]);
            o[i] = (_Float16)((v > 0.f) ? v : 0.f);
        }
        *(half8*)&x1[(size_t)n * HDIM + c1] = o;
    }
}

// ---------------- GCN gather: 2 waves per node (edge-split), LDS combine ----------------
__global__ __launch_bounds__(256) void k_gcn_gather(
    const int* __restrict__ rowptr, const int* __restrict__ csr,
    const float* __restrict__ wn, const _Float16* __restrict__ x1,
    _Float16* __restrict__ t)
{
    __shared__ float lsh[2][640];
    const int wv = threadIdx.x >> 6, lane = threadIdx.x & 63;
    const int sub = wv >> 1, half = wv & 1;
    const int n = blockIdx.x * 2 + sub;
    const int c0 = lane * 8;
    const bool dual = (lane < 16);
    const int c1 = 512 + lane * 8;

    float acc0[8], acc1[8];
    #pragma unroll
    for (int i = 0; i < 8; ++i) { acc0[i] = 0.f; acc1[i] = 0.f; }

    const int r0 = rowptr[n], r1 = rowptr[n + 1];
    const int mid = (r0 + r1 + 1) >> 1;
    const int j0 = half ? mid : r0;
    const int j1 = half ? r1 : mid;
    int j = j0;
    for (; j + 3 < j1; j += 4) {
        const int sA = csr[j], sB = csr[j + 1], sC = csr[j + 2], sD = csr[j + 3];
        const float wA = wn[j], wB = wn[j + 1], wC = wn[j + 2], wD = wn[j + 3];
        const half8 vA0 = *(const half8*)&x1[(size_t)sA * HDIM + c0];
        const half8 vB0 = *(const half8*)&x1[(size_t)sB * HDIM + c0];
        const half8 vC0 = *(const half8*)&x1[(size_t)sC * HDIM + c0];
        const half8 vD0 = *(const half8*)&x1[(size_t)sD * HDIM + c0];
        #pragma unroll
        for (int i = 0; i < 8; ++i) {
            acc0[i] = fmaf(wA, (float)vA0[i], acc0[i]);
            acc0[i] = fmaf(wB, (float)vB0[i], acc0[i]);
            acc0[i] = fmaf(wC, (float)vC0[i], acc0[i]);
            acc0[i] = fmaf(wD, (float)vD0[i], acc0[i]);
        }
        if (dual) {
            const half8 vA1 = *(const half8*)&x1[(size_t)sA * HDIM + c1];
            const half8 vB1 = *(const half8*)&x1[(size_t)sB * HDIM + c1];
            const half8 vC1 = *(const half8*)&x1[(size_t)sC * HDIM + c1];
            const half8 vD1 = *(const half8*)&x1[(size_t)sD * HDIM + c1];
            #pragma unroll
            for (int i = 0; i < 8; ++i) {
                acc1[i] = fmaf(wA, (float)vA1[i], acc1[i]);
                acc1[i] = fmaf(wB, (float)vB1[i], acc1[i]);
                acc1[i] = fmaf(wC, (float)vC1[i], acc1[i]);
                acc1[i] = fmaf(wD, (float)vD1[i], acc1[i]);
            }
        }
    }
    for (; j < j1; ++j) {
        const int sA = csr[j];
        const float wA = wn[j];
        const half8 vA0 = *(const half8*)&x1[(size_t)sA * HDIM + c0];
        #pragma unroll
        for (int i = 0; i < 8; ++i) acc0[i] = fmaf(wA, (float)vA0[i], acc0[i]);
        if (dual) {
            const half8 vA1 = *(const half8*)&x1[(size_t)sA * HDIM + c1];
            #pragma unroll
            for (int i = 0; i < 8; ++i) acc1[i] = fmaf(wA, (float)vA1[i], acc1[i]);
        }
    }

    if (half) {
        float* p = lsh[sub];
        #pragma unroll
        for (int i = 0; i < 8; ++i) p[c0 + i] = acc0[i];
        if (dual) {
            #pragma unroll
            for (int i = 0; i < 8; ++i) p[c1 + i] = acc1[i];
        }
    }
    __syncthreads();
    if (half) return;
    {
        const float* p = lsh[sub];
        #pragma unroll
        for (int i = 0; i < 8; ++i) acc0[i] += p[c0 + i];
        if (dual) {
            #pragma unroll
            for (int i = 0; i < 8; ++i) acc1[i] += p[c1 + i];
        }
    }

    {
        half8 o;
        #pragma unroll
        for (int i = 0; i < 8; ++i) o[i] = (_Float16)acc0[i];
        *(half8*)&t[(size_t)n * HDIM + c0] = o;
    }
    if (dual) {
        half8 o;
        #pragma unroll
        for (int i = 0; i < 8; ++i) o[i] = (_Float16)acc1[i];
        *(half8*)&t[(size_t)n * HDIM + c1] = o;
    }
}

// ---------------- GEMM2 (m97-style) + fused bias/relu/pool ----------------
__global__ __launch_bounds__(256) void k_gemm2(const _Float16* __restrict__ X,
                                               const _Float16* __restrict__ Wbt,
                                               const float* __restrict__ b_gcn,
                                               float* __restrict__ pmax,
                                               float* __restrict__ psum)
{
    __shared__ _Float16 Bs[128 * BKK];
    const int tid = threadIdx.x;
    const int lane = tid & 63, wave = tid >> 6;
    const int l15 = lane & 15, quad = lane >> 4;
    const int m0 = blockIdx.x * 128 + wave * 32;
    const int n0 = blockIdx.y * 128;
    const int l7 = l15 & 7;

    f32x4 acc[2][8];
    #pragma unroll
    for (int r = 0; r < 2; ++r)
        #pragma unroll
        for (int c = 0; c < 8; ++c) acc[r][c] = (f32x4){0.f, 0.f, 0.f, 0.f};

    const int jrow = lane >> 4;
    const int jchunk = lane & 15;

    const _Float16* a0p = &X[(size_t)(m0 + l15) * HDIM + quad * 8];
    const _Float16* a1p = a0p + (size_t)16 * HDIM;

    for (int kb = 0; kb < HDIM; kb += BKK) {
        #pragma unroll
        for (int i = 0; i < 8; ++i) {
            const int r = (wave * 8 + i) * 4 + jrow;
            const int ck = jchunk ^ (r & 7);
            const _Float16* src = &Wbt[(size_t)(n0 + r) * HDIM + kb + ck * 8];
            __builtin_amdgcn_global_load_lds(
                (const __attribute__((address_space(1))) void*)src,
                (__attribute__((address_space(3))) void*)&Bs[(size_t)(wave * 8 + i) * 512],
                16, 0, 0);
        }
        half8 a0[4], a1[4];
        #pragma unroll
        for (int ks = 0; ks < 4; ++ks) {
            a0[ks] = *(const half8*)(a0p + kb + ks * 32);
            a1[ks] = *(const half8*)(a1p + kb + ks * 32);
        }
        __syncthreads();
        #pragma unroll
        for (int ks = 0; ks < 4; ++ks) {
            #pragma unroll
            for (int c = 0; c < 8; ++c) {
                const int br = c * 16 + l15;
                const int ck = (4 * ks + quad) ^ l7;
                const half8 b = *(const half8*)&Bs[(size_t)br * BKK + ck * 8];
                acc[0][c] = __builtin_amdgcn_mfma_f32_16x16x32_f16(a0[ks], b, acc[0][c], 0, 0, 0);
                acc[1][c] = __builtin_amdgcn_mfma_f32_16x16x32_f16(a1[ks], b, acc[1][c], 0, 0, 0);
            }
        }
        __syncthreads();
    }

    float lmax[8], lsum[8];
    #pragma unroll
    for (int c = 0; c < 8; ++c) { lmax[c] = 0.f; lsum[c] = 0.f; }
    #pragma unroll
    for (int c = 0; c < 8; ++c) {
        const float bb = b_gcn[n0 + c * 16 + l15];
        #pragma unroll
        for (int r = 0; r < 2; ++r)
            #pragma unroll
            for (int g = 0; g < 4; ++g) {
                const int row = m0 + r * 16 + quad * 4 + g;
                if (row < NN) {
                    float v = acc[r][c][g] + bb;
                    v = (v > 0.f) ? v : 0.f;
                    lmax[c] = fmaxf(lmax[c], v);
                    lsum[c] += v;
                }
            }
    }
    float* redm = (float*)Bs;
    float* reds = redm + 128;
    if (tid < 128) { redm[tid] = 0.f; reds[tid] = 0.f; }
    __syncthreads();
    #pragma unroll
    for (int c = 0; c < 8; ++c) {
        const int col = c * 16 + l15;
        atomicMax((int*)&redm[col], __float_as_int(lmax[c]));
        atomicAdd(&reds[col], lsum[c]);
    }
    __syncthreads();
    if (tid < 128) {
        atomicMax((int*)&pmax[n0 + tid], __float_as_int(redm[tid]));
        atomicAdd(&psum[n0 + tid], reds[tid]);
    }
}

// ---------------- fused MLP (layer1 split-K + last-block layer2) ----------------
__global__ __launch_bounds__(256) void k_mlp(const float* __restrict__ pmax,
                                             const float* __restrict__ psum,
                                             const float* __restrict__ W1,
                                             const float* __restrict__ b1,
                                             const float* __restrict__ W2,
                                             const float* __restrict__ b2,
                                             float* __restrict__ hacc,
                                             int* __restrict__ ticket,
                                             float* __restrict__ out)
{
    __shared__ float pl[80];
    __shared__ int lastf;
    const int t = threadIdx.x;
    const int i0 = blockIdx.y * 80;
    if (t < 80) {
        const int i = i0 + t;
        pl[t] = (i < HDIM) ? pmax[i] : psum[i - HDIM] * (1.0f / NN);
    }
    __syncthreads();
    const int j = blockIdx.x * 256 + t;
    if (j < H1) {
        float acc = 0.f;
        #pragma unroll 8
        for (int i = 0; i < 80; ++i)
            acc = fmaf(pl[i], W1[(size_t)(i0 + i) * H1 + j], acc);
        atomicAdd(&hacc[j], acc);
    }
    __threadfence();
    if (t == 0)
        lastf = (atomicAdd(ticket, 1) == (int)(gridDim.x * gridDim.y) - 1);
    __syncthreads();
    if (!lastf) return;
    __threadfence();

    __shared__ float hsh[H1];
    __shared__ float red[256];
    for (int i = t; i < H1; i += 256) {
        const float v = hacc[i] + b1[i];
        hsh[i] = (v > 0.f) ? v : 0.f;
    }
    __syncthreads();
    float acc[10];
    #pragma unroll
    for (int k = 0; k < 10; ++k) acc[k] = 0.f;
    for (int i = t; i < H1; i += 256) {
        const float h = hsh[i];
        #pragma unroll
        for (int k = 0; k < 10; ++k) acc[k] = fmaf(h, W2[i * 10 + k], acc[k]);
    }
    for (int k = 0; k < 10; ++k) {
        red[t] = acc[k]; __syncthreads();
        for (int s2 = 128; s2 > 0; s2 >>= 1) {
            if (t < s2) red[t] += red[t + s2];
            __syncthreads();
        }
        if (t == 0) out[k] = red[0] + b2[k];
        __syncthreads();
    }
}

// ---------------- launch ----------------
extern "C" void kernel_launch(void* const* d_in, const int* in_sizes, int n_in,
                              void* d_out, int out_size, void* d_ws, size_t ws_size,
                              hipStream_t stream)
{
    const float* x     = (const float*)d_in[0];
    const float* Wg    = (const float*)d_in[1];
    const float* att_s = (const float*)d_in[2];
    const float* att_d = (const float*)d_in[3];
    const float* b_gat = (const float*)d_in[4];
    const float* Wgcn  = (const float*)d_in[5];
    const float* b_gcn = (const float*)d_in[6];
    const float* W1    = (const float*)d_in[7];
    const float* b1    = (const float*)d_in[8];
    const float* W2    = (const float*)d_in[9];
    const float* b2    = (const float*)d_in[10];
    const int*   ei    = (const int*)d_in[11];
    const int E = in_sizes[11] / 2;
    const int EP = E + NN;
    float* out = (float*)d_out;

    char* wsp = (char*)d_ws;
    size_t off = 0;
    auto alc = [&](size_t b) { void* p = wsp + off; off += (b + 255) & ~(size_t)255; return p; };
    _Float16* bufA = (_Float16*)alc((size_t)NN * HDIM * 2);  // xl, later t
    _Float16* bufB = (_Float16*)alc((size_t)NN * HDIM * 2);  // x1
    float* aS     = (float*)alc((size_t)NN * ASTRIDE * 4);
    float* aD     = (float*)alc((size_t)NN * ASTRIDE * 4);
    int*   rowptr = (int*)alc((size_t)(NN + 1) * 4);
    int*   csr    = (int*)alc((size_t)EP * 4);
    float* dinv   = (float*)alc((size_t)NN * 4);
    float* wn     = (float*)alc((size_t)EP * 4);
    float* wgat   = (float*)alc((size_t)EP * HH * 4);        // [edge][head]
    _Float16* Wbt = (_Float16*)alc((size_t)HDIM * HDIM * 2); // W_gcn^T fp16
    _Float16* WgT = (_Float16*)alc((size_t)HDIM * DD * 2);   // W_gat^T fp16 [640][64]
    // zero-initialized region (single memset): cnt | cursor | pmax | psum | hacc | ticket
    const size_t zoff = off;
    int*   cnt    = (int*)alc((size_t)NN * 4);
    int*   cursor = (int*)alc((size_t)NN * 4);
    float* pmax   = (float*)alc((size_t)HDIM * 4);
    float* psum   = (float*)alc((size_t)HDIM * 4);
    float* hacc   = (float*)alc((size_t)H1 * 4);
    int*   tks    = (int*)alc(2 * 4);
    const size_t zsize = off - zoff;

    hipMemsetAsync(cnt, 0, zsize, stream);

    dim3 gw(HDIM / 32, HDIM / 32 + DD / 32);
    k_cvtB<<<gw, 256, 0, stream>>>(Wgcn, Wg, Wbt, WgT);
    dim3 g1((NN + 127) / 128, HH);
    k_gemm1<<<g1, 256, 0, stream>>>(x, WgT, att_s, att_d, bufA, aS, aD);
    k_count<<<(EP + 255) / 256, 256, 0, stream>>>(ei, E, cnt);
    k_scan<<<1, 1024, 0, stream>>>(cnt, rowptr, dinv);
    k_fill<<<(EP + 255) / 256, 256, 0, stream>>>(ei, E, rowptr, cursor, csr,
                                                 dinv, wn, aS, aD, wgat);
    k_gat_gather<<<NN / 2, 256, 0, stream>>>(rowptr, csr, wgat, bufA, b_gat, bufB);
    k_gcn_gather<<<NN / 2, 256, 0, stream>>>(rowptr, csr, wn, bufB, bufA);
    dim3 g2((NN + 127) / 128, HDIM / 128);
    k_gemm2<<<g2, 256, 0, stream>>>(bufA, Wbt, b_gcn, pmax, psum);
    dim3 gm1(6, 16);
    k_mlp<<<gm1, 256, 0, stream>>>(pmax, psum, W1, b1, W2, b2, hacc, tks + 1, out);
}

// Round 15
// 373.846 us; speedup vs baseline: 1.1953x; 1.0107x over previous
//
#include <hip/hip_runtime.h>
#include <hip/hip_bf16.h>
#include <math.h>

#define NN 20000
#define DD 64
#define HH 10
#define HDIM 640
#define NEG 0.2f
#define H1 1500
#define ASTRIDE 12   // a_src/a_dst row stride (floats): 48B, 16B-aligned
#define BKK 128      // gemm2 K-tile

typedef _Float16 half8 __attribute__((ext_vector_type(8)));
typedef _Float16 half4v __attribute__((ext_vector_type(4)));
typedef _Float16 half2v __attribute__((ext_vector_type(2)));
typedef float f32x4 __attribute__((ext_vector_type(4)));

// ---------------- both weight transposes in one launch ----------------
__global__ __launch_bounds__(256) void k_cvtB(const float* __restrict__ Wgcn,
                                              const float* __restrict__ Wg,
                                              _Float16* __restrict__ Wbt,
                                              _Float16* __restrict__ WgT)
{
    __shared__ float t[32][33];
    const int bx = blockIdx.x;
    int by = blockIdx.y;
    const float* W; _Float16* WT; int rows, cols;
    if (by < 20) { W = Wgcn; WT = Wbt; rows = HDIM; cols = HDIM; }
    else         { W = Wg;   WT = WgT; rows = DD;   cols = HDIM; by -= 20; }
    const int lx = threadIdx.x & 31, ly = threadIdx.x >> 5;
    #pragma unroll
    for (int i = ly; i < 32; i += 8)
        t[i][lx] = W[(size_t)(by * 32 + i) * cols + bx * 32 + lx];
    __syncthreads();
    #pragma unroll
    for (int j = ly; j < 32; j += 8)
        WT[(size_t)(bx * 32 + j) * rows + by * 32 + lx] = (_Float16)t[lx][j];
}

// ---------------- GEMM1 (MFMA fp16): xl = x @ W_gat, fused a_src/a_dst dots ----------------
__global__ __launch_bounds__(256) void k_gemm1(
    const float* __restrict__ x, const _Float16* __restrict__ WgT,
    const float* __restrict__ att_s, const float* __restrict__ att_d,
    _Float16* __restrict__ xl, float* __restrict__ a_src, float* __restrict__ a_dst)
{
    __shared__ _Float16 As[128][72];
    __shared__ _Float16 Bs[64][72];
    const int tid = threadIdx.x;
    const int m0 = blockIdx.x * 128;
    const int h  = blockIdx.y;
    const int n0 = h * 64;

    {
        const int row = tid >> 1, ch = (tid & 1) * 32;
        const int gr = m0 + row;
        if (gr < NN) {
            const float* xp = &x[(size_t)gr * DD + ch];
            #pragma unroll
            for (int i = 0; i < 8; ++i) {
                const float4 v = *(const float4*)&xp[i * 4];
                half4v o = {(_Float16)v.x, (_Float16)v.y, (_Float16)v.z, (_Float16)v.w};
                *(half4v*)&As[row][ch + i * 4] = o;
            }
        } else {
            const half8 z = {0, 0, 0, 0, 0, 0, 0, 0};
            #pragma unroll
            for (int i = 0; i < 4; ++i) *(half8*)&As[row][ch + i * 8] = z;
        }
    }
    {
        const int row = tid >> 2, part = (tid & 3) * 16;
        const _Float16* wp = &WgT[(size_t)(n0 + row) * DD + part];
        *(half8*)&Bs[row][part]     = *(const half8*)&wp[0];
        *(half8*)&Bs[row][part + 8] = *(const half8*)&wp[8];
    }
    __syncthreads();

    const int lane = tid & 63, wave = tid >> 6;
    const int l15 = lane & 15, quad = lane >> 4;
    f32x4 acc[2][4];
    #pragma unroll
    for (int r = 0; r < 2; ++r)
        #pragma unroll
        for (int c = 0; c < 4; ++c) acc[r][c] = (f32x4){0.f, 0.f, 0.f, 0.f};

    #pragma unroll
    for (int ks = 0; ks < 2; ++ks) {
        const half8 a0 = *(const half8*)&As[wave * 32 + l15][ks * 32 + quad * 8];
        const half8 a1 = *(const half8*)&As[wave * 32 + 16 + l15][ks * 32 + quad * 8];
        #pragma unroll
        for (int c = 0; c < 4; ++c) {
            const half8 b = *(const half8*)&Bs[c * 16 + l15][ks * 32 + quad * 8];
            acc[0][c] = __builtin_amdgcn_mfma_f32_16x16x32_f16(a0, b, acc[0][c], 0, 0, 0);
            acc[1][c] = __builtin_amdgcn_mfma_f32_16x16x32_f16(a1, b, acc[1][c], 0, 0, 0);
        }
    }

    float asv[4], adv[4];
    #pragma unroll
    for (int c = 0; c < 4; ++c) {
        asv[c] = att_s[h * DD + c * 16 + l15];
        adv[c] = att_d[h * DD + c * 16 + l15];
    }
    #pragma unroll
    for (int r = 0; r < 2; ++r) {
        float ps[4] = {0.f, 0.f, 0.f, 0.f}, pd[4] = {0.f, 0.f, 0.f, 0.f};
        #pragma unroll
        for (int c = 0; c < 4; ++c)
            #pragma unroll
            for (int g = 0; g < 4; ++g) {
                ps[g] = fmaf(acc[r][c][g], asv[c], ps[g]);
                pd[g] = fmaf(acc[r][c][g], adv[c], pd[g]);
            }
        #pragma unroll
        for (int m = 1; m <= 8; m <<= 1)
            #pragma unroll
            for (int g = 0; g < 4; ++g) {
                ps[g] += __shfl_xor(ps[g], m);
                pd[g] += __shfl_xor(pd[g], m);
            }
        #pragma unroll
        for (int c = 0; c < 4; ++c)
            #pragma unroll
            for (int g = 0; g < 4; ++g) {
                const int row = m0 + wave * 32 + r * 16 + quad * 4 + g;
                if (row < NN)
                    xl[(size_t)row * HDIM + n0 + c * 16 + l15] = (_Float16)acc[r][c][g];
            }
        if (l15 == 0)
            #pragma unroll
            for (int g = 0; g < 4; ++g) {
                const int row = m0 + wave * 32 + r * 16 + quad * 4 + g;
                if (row < NN) {
                    a_src[(size_t)row * ASTRIDE + h] = ps[g];
                    a_dst[(size_t)row * ASTRIDE + h] = pd[g];
                }
            }
    }
}

// ---------------- CSR build ----------------
__global__ void k_count(const int* __restrict__ ei, int E, int* __restrict__ cnt)
{
    const int e = blockIdx.x * blockDim.x + threadIdx.x;
    if (e >= E + NN) return;
    const int d = (e < E) ? ei[E + e] : (e - E);
    atomicAdd(&cnt[d], 1);
}

__global__ __launch_bounds__(1024) void k_scan(const int* __restrict__ cnt,
                                               int* __restrict__ rowptr,
                                               float* __restrict__ dinv)
{
    __shared__ int sh[1024];
    const int t = threadIdx.x;
    const int CH = 20;
    const int base = t * CH;
    int loc[CH];
    int s = 0;
    #pragma unroll
    for (int i = 0; i < CH; ++i) {
        const int idx = base + i;
        const int c = (idx < NN) ? cnt[idx] : 0;
        loc[i] = s; s += c;
    }
    sh[t] = s; __syncthreads();
    for (int off = 1; off < 1024; off <<= 1) {
        const int v = (t >= off) ? sh[t - off] : 0;
        __syncthreads();
        sh[t] += v;
        __syncthreads();
    }
    const int prev = (t == 0) ? 0 : sh[t - 1];
    #pragma unroll
    for (int i = 0; i < CH; ++i) {
        const int idx = base + i;
        if (idx < NN) {
            rowptr[idx] = prev + loc[i];
            dinv[idx]   = rsqrtf((float)cnt[idx]);
        }
    }
    if (t == 1023) rowptr[NN] = sh[1023];
}

// ---------------- fill CSR + GCN norm + GAT edge weights ----------------
__global__ void k_fill(const int* __restrict__ ei, int E,
                       const int* __restrict__ rowptr,
                       int* __restrict__ cursor, int* __restrict__ csr,
                       const float* __restrict__ dinv, float* __restrict__ wn,
                       const float* __restrict__ aS, const float* __restrict__ aD,
                       float* __restrict__ wgat)
{
    const int e = blockIdx.x * blockDim.x + threadIdx.x;
    if (e >= E + NN) return;
    int s, d;
    if (e < E) { s = ei[e]; d = ei[E + e]; } else { s = d = e - E; }
    const int pos = atomicAdd(&cursor[d], 1);
    const int idx = rowptr[d] + pos;
    csr[idx] = s;
    wn[idx]  = dinv[s] * dinv[d];

    const f32x4 s0 = *(const f32x4*)&aS[(size_t)s * ASTRIDE];
    const f32x4 s1 = *(const f32x4*)&aS[(size_t)s * ASTRIDE + 4];
    const float2 s2 = *(const float2*)&aS[(size_t)s * ASTRIDE + 8];
    const f32x4 d0 = *(const f32x4*)&aD[(size_t)d * ASTRIDE];
    const f32x4 d1 = *(const f32x4*)&aD[(size_t)d * ASTRIDE + 4];
    const float2 d2 = *(const float2*)&aD[(size_t)d * ASTRIDE + 8];
    const float av[10] = {s0.x + d0.x, s0.y + d0.y, s0.z + d0.z, s0.w + d0.w,
                          s1.x + d1.x, s1.y + d1.y, s1.z + d1.z, s1.w + d1.w,
                          s2.x + d2.x, s2.y + d2.y};
    float* wp = &wgat[(size_t)idx * HH];
    #pragma unroll
    for (int h = 0; h < 10; ++h) {
        float a = av[h];
        a = (a >= 0.f) ? a : NEG * a;
        wp[h] = __expf(a);
    }
}

// ---------------- GAT gather: wave per node, unroll 4, den in-flight (R11 form) ----------------
__global__ __launch_bounds__(256) void k_gat_gather(
    const int* __restrict__ rowptr, const int* __restrict__ csr,
    const float* __restrict__ wgat, const _Float16* __restrict__ xl,
    const float* __restrict__ b_gat, _Float16* __restrict__ x1)
{
    const int wave = threadIdx.x >> 6, lane = threadIdx.x & 63;
    const int n = blockIdx.x * 4 + wave;
    const int c0 = lane * 8;
    const int h0 = lane >> 3;
    const bool dual = (lane < 16);
    const int c1 = 512 + lane * 8;
    const int h1 = 8 + (lane >> 3);

    float acc0[8], acc1[8], ws0 = 0.f, ws1 = 0.f;
    #pragma unroll
    for (int i = 0; i < 8; ++i) { acc0[i] = 0.f; acc1[i] = 0.f; }

    const int j0 = rowptr[n], j1 = rowptr[n + 1];
    int j = j0;
    for (; j + 3 < j1; j += 4) {
        const int sA = csr[j], sB = csr[j + 1], sC = csr[j + 2], sD = csr[j + 3];
        const float wA0 = wgat[(size_t)(j + 0) * HH + h0];
        const float wB0 = wgat[(size_t)(j + 1) * HH + h0];
        const float wC0 = wgat[(size_t)(j + 2) * HH + h0];
        const float wD0 = wgat[(size_t)(j + 3) * HH + h0];
        ws0 += wA0 + wB0 + wC0 + wD0;
        const half8 vA0 = *(const half8*)&xl[(size_t)sA * HDIM + c0];
        const half8 vB0 = *(const half8*)&xl[(size_t)sB * HDIM + c0];
        const half8 vC0 = *(const half8*)&xl[(size_t)sC * HDIM + c0];
        const half8 vD0 = *(const half8*)&xl[(size_t)sD * HDIM + c0];
        #pragma unroll
        for (int i = 0; i < 8; ++i) {
            acc0[i] = fmaf(wA0, (float)vA0[i], acc0[i]);
            acc0[i] = fmaf(wB0, (float)vB0[i], acc0[i]);
            acc0[i] = fmaf(wC0, (float)vC0[i], acc0[i]);
            acc0[i] = fmaf(wD0, (float)vD0[i], acc0[i]);
        }
        if (dual) {
            const float wA1 = wgat[(size_t)(j + 0) * HH + h1];
            const float wB1 = wgat[(size_t)(j + 1) * HH + h1];
            const float wC1 = wgat[(size_t)(j + 2) * HH + h1];
            const float wD1 = wgat[(size_t)(j + 3) * HH + h1];
            ws1 += wA1 + wB1 + wC1 + wD1;
            const half8 vA1 = *(const half8*)&xl[(size_t)sA * HDIM + c1];
            const half8 vB1 = *(const half8*)&xl[(size_t)sB * HDIM + c1];
            const half8 vC1 = *(const half8*)&xl[(size_t)sC * HDIM + c1];
            const half8 vD1 = *(const half8*)&xl[(size_t)sD * HDIM + c1];
            #pragma unroll
            for (int i = 0; i < 8; ++i) {
                acc1[i] = fmaf(wA1, (float)vA1[i], acc1[i]);
                acc1[i] = fmaf(wB1, (float)vB1[i], acc1[i]);
                acc1[i] = fmaf(wC1, (float)vC1[i], acc1[i]);
                acc1[i] = fmaf(wD1, (float)vD1[i], acc1[i]);
            }
        }
    }
    for (; j < j1; ++j) {
        const int sA = csr[j];
        const float wA0 = wgat[(size_t)j * HH + h0];
        ws0 += wA0;
        const half8 vA0 = *(const half8*)&xl[(size_t)sA * HDIM + c0];
        #pragma unroll
        for (int i = 0; i < 8; ++i) acc0[i] = fmaf(wA0, (float)vA0[i], acc0[i]);
        if (dual) {
            const float wA1 = wgat[(size_t)j * HH + h1];
            ws1 += wA1;
            const half8 vA1 = *(const half8*)&xl[(size_t)sA * HDIM + c1];
            #pragma unroll
            for (int i = 0; i < 8; ++i) acc1[i] = fmaf(wA1, (float)vA1[i], acc1[i]);
        }
    }

    {
        const float rr = 1.f / (ws0 + 1e-16f);
        const float4 ba = *(const float4*)&b_gat[c0];
        const float4 bb = *(const float4*)&b_gat[c0 + 4];
        const float bv[8] = {ba.x, ba.y, ba.z, ba.w, bb.x, bb.y, bb.z, bb.w};
        half8 o;
        #pragma unroll
        for (int i = 0; i < 8; ++i) {
            const float v = fmaf(acc0[i], rr, bv[i]);
            o[i] = (_Float16)((v > 0.f) ? v : 0.f);
        }
        *(half8*)&x1[(size_t)n * HDIM + c0] = o;
    }
    if (dual) {
        const float rr = 1.f / (ws1 + 1e-16f);
        const float4 ba = *(const float4*)&b_gat[c1];
        const float4 bb = *(const float4*)&b_gat[c1 + 4];
        const float bv[8] = {ba.x, ba.y, ba.z, ba.w, bb.x, bb.y, bb.z, bb.w};
        half8 o;
        #pragma unroll
        for (int i = 0; i < 8; ++i) {
            const float v = fmaf(acc1[i], rr, bv[i]);
            o[i] = (_Float16)((v > 0.f) ? v : 0.f);
        }
        *(half8*)&x1[(size_t)n * HDIM + c1] = o;
    }
}

// ---------------- GCN gather (reordered): t = segsum(wn * x1[src]), R11 form ----------------
__global__ __launch_bounds__(256) void k_gcn_gather(
    const int* __restrict__ rowptr, const int* __restrict__ csr,
    const float* __restrict__ wn, const _Float16* __restrict__ x1,
    _Float16* __restrict__ t)
{
    const int wave = threadIdx.x >> 6, lane = threadIdx.x & 63;
    const int n = blockIdx.x * 4 + wave;
    const int c0 = lane * 8;
    const bool dual = (lane < 16);
    const int c1 = 512 + lane * 8;

    float acc0[8], acc1[8];
    #pragma unroll
    for (int i = 0; i < 8; ++i) { acc0[i] = 0.f; acc1[i] = 0.f; }

    const int j0 = rowptr[n], j1 = rowptr[n + 1];
    int j = j0;
    for (; j + 3 < j1; j += 4) {
        const int sA = csr[j], sB = csr[j + 1], sC = csr[j + 2], sD = csr[j + 3];
        const float wA = wn[j], wB = wn[j + 1], wC = wn[j + 2], wD = wn[j + 3];
        const half8 vA0 = *(const half8*)&x1[(size_t)sA * HDIM + c0];
        const half8 vB0 = *(const half8*)&x1[(size_t)sB * HDIM + c0];
        const half8 vC0 = *(const half8*)&x1[(size_t)sC * HDIM + c0];
        const half8 vD0 = *(const half8*)&x1[(size_t)sD * HDIM + c0];
        #pragma unroll
        for (int i = 0; i < 8; ++i) {
            acc0[i] = fmaf(wA, (float)vA0[i], acc0[i]);
            acc0[i] = fmaf(wB, (float)vB0[i], acc0[i]);
            acc0[i] = fmaf(wC, (float)vC0[i], acc0[i]);
            acc0[i] = fmaf(wD, (float)vD0[i], acc0[i]);
        }
        if (dual) {
            const half8 vA1 = *(const half8*)&x1[(size_t)sA * HDIM + c1];
            const half8 vB1 = *(const half8*)&x1[(size_t)sB * HDIM + c1];
            const half8 vC1 = *(const half8*)&x1[(size_t)sC * HDIM + c1];
            const half8 vD1 = *(const half8*)&x1[(size_t)sD * HDIM + c1];
            #pragma unroll
            for (int i = 0; i < 8; ++i) {
                acc1[i] = fmaf(wA, (float)vA1[i], acc1[i]);
                acc1[i] = fmaf(wB, (float)vB1[i], acc1[i]);
                acc1[i] = fmaf(wC, (float)vC1[i], acc1[i]);
                acc1[i] = fmaf(wD, (float)vD1[i], acc1[i]);
            }
        }
    }
    for (; j < j1; ++j) {
        const int sA = csr[j];
        const float wA = wn[j];
        const half8 vA0 = *(const half8*)&x1[(size_t)sA * HDIM + c0];
        #pragma unroll
        for (int i = 0; i < 8; ++i) acc0[i] = fmaf(wA, (float)vA0[i], acc0[i]);
        if (dual) {
            const half8 vA1 = *(const half8*)&x1[(size_t)sA * HDIM + c1];
            #pragma unroll
            for (int i = 0; i < 8; ++i) acc1[i] = fmaf(wA, (float)vA1[i], acc1[i]);
        }
    }

    {
        half8 o;
        #pragma unroll
        for (int i = 0; i < 8; ++i) o[i] = (_Float16)acc0[i];
        *(half8*)&t[(size_t)n * HDIM + c0] = o;
    }
    if (dual) {
        half8 o;
        #pragma unroll
        for (int i = 0; i < 8; ++i) o[i] = (_Float16)acc1[i];
        *(half8*)&t[(size_t)n * HDIM + c1] = o;
    }
}

// ---------------- GEMM2 (m97-style) + fused bias/relu/pool ----------------
__global__ __launch_bounds__(256) void k_gemm2(const _Float16* __restrict__ X,
                                               const _Float16* __restrict__ Wbt,
                                               const float* __restrict__ b_gcn,
                                               float* __restrict__ pmax,
                                               float* __restrict__ psum)
{
    __shared__ _Float16 Bs[128 * BKK];
    const int tid = threadIdx.x;
    const int lane = tid & 63, wave = tid >> 6;
    const int l15 = lane & 15, quad = lane >> 4;
    const int m0 = blockIdx.x * 128 + wave * 32;
    const int n0 = blockIdx.y * 128;
    const int l7 = l15 & 7;

    f32x4 acc[2][8];
    #pragma unroll
    for (int r = 0; r < 2; ++r)
        #pragma unroll
        for (int c = 0; c < 8; ++c) acc[r][c] = (f32x4){0.f, 0.f, 0.f, 0.f};

    const int jrow = lane >> 4;
    const int jchunk = lane & 15;

    const _Float16* a0p = &X[(size_t)(m0 + l15) * HDIM + quad * 8];
    const _Float16* a1p = a0p + (size_t)16 * HDIM;

    for (int kb = 0; kb < HDIM; kb += BKK) {
        #pragma unroll
        for (int i = 0; i < 8; ++i) {
            const int r = (wave * 8 + i) * 4 + jrow;
            const int ck = jchunk ^ (r & 7);
            const _Float16* src = &Wbt[(size_t)(n0 + r) * HDIM + kb + ck * 8];
            __builtin_amdgcn_global_load_lds(
                (const __attribute__((address_space(1))) void*)src,
                (__attribute__((address_space(3))) void*)&Bs[(size_t)(wave * 8 + i) * 512],
                16, 0, 0);
        }
        half8 a0[4], a1[4];
        #pragma unroll
        for (int ks = 0; ks < 4; ++ks) {
            a0[ks] = *(const half8*)(a0p + kb + ks * 32);
            a1[ks] = *(const half8*)(a1p + kb + ks * 32);
        }
        __syncthreads();
        #pragma unroll
        for (int ks = 0; ks < 4; ++ks) {
            #pragma unroll
            for (int c = 0; c < 8; ++c) {
                const int br = c * 16 + l15;
                const int ck = (4 * ks + quad) ^ l7;
                const half8 b = *(const half8*)&Bs[(size_t)br * BKK + ck * 8];
                acc[0][c] = __builtin_amdgcn_mfma_f32_16x16x32_f16(a0[ks], b, acc[0][c], 0, 0, 0);
                acc[1][c] = __builtin_amdgcn_mfma_f32_16x16x32_f16(a1[ks], b, acc[1][c], 0, 0, 0);
            }
        }
        __syncthreads();
    }

    float lmax[8], lsum[8];
    #pragma unroll
    for (int c = 0; c < 8; ++c) { lmax[c] = 0.f; lsum[c] = 0.f; }
    #pragma unroll
    for (int c = 0; c < 8; ++c) {
        const float bb = b_gcn[n0 + c * 16 + l15];
        #pragma unroll
        for (int r = 0; r < 2; ++r)
            #pragma unroll
            for (int g = 0; g < 4; ++g) {
                const int row = m0 + r * 16 + quad * 4 + g;
                if (row < NN) {
                    float v = acc[r][c][g] + bb;
                    v = (v > 0.f) ? v : 0.f;
                    lmax[c] = fmaxf(lmax[c], v);
                    lsum[c] += v;
                }
            }
    }
    float* redm = (float*)Bs;
    float* reds = redm + 128;
    if (tid < 128) { redm[tid] = 0.f; reds[tid] = 0.f; }
    __syncthreads();
    #pragma unroll
    for (int c = 0; c < 8; ++c) {
        const int col = c * 16 + l15;
        atomicMax((int*)&redm[col], __float_as_int(lmax[c]));
        atomicAdd(&reds[col], lsum[c]);
    }
    __syncthreads();
    if (tid < 128) {
        atomicMax((int*)&pmax[n0 + tid], __float_as_int(redm[tid]));
        atomicAdd(&psum[n0 + tid], reds[tid]);
    }
}

// ---------------- fused MLP (layer1 split-K + last-block layer2) ----------------
__global__ __launch_bounds__(256) void k_mlp(const float* __restrict__ pmax,
                                             const float* __restrict__ psum,
                                             const float* __restrict__ W1,
                                             const float* __restrict__ b1,
                                             const float* __restrict__ W2,
                                             const float* __restrict__ b2,
                                             float* __restrict__ hacc,
                                             int* __restrict__ ticket,
                                             float* __restrict__ out)
{
    __shared__ float pl[80];
    __shared__ int lastf;
    const int t = threadIdx.x;
    const int i0 = blockIdx.y * 80;
    if (t < 80) {
        const int i = i0 + t;
        pl[t] = (i < HDIM) ? pmax[i] : psum[i - HDIM] * (1.0f / NN);
    }
    __syncthreads();
    const int j = blockIdx.x * 256 + t;
    if (j < H1) {
        float acc = 0.f;
        #pragma unroll 8
        for (int i = 0; i < 80; ++i)
            acc = fmaf(pl[i], W1[(size_t)(i0 + i) * H1 + j], acc);
        atomicAdd(&hacc[j], acc);
    }
    __threadfence();
    if (t == 0)
        lastf = (atomicAdd(ticket, 1) == (int)(gridDim.x * gridDim.y) - 1);
    __syncthreads();
    if (!lastf) return;
    __threadfence();

    __shared__ float hsh[H1];
    __shared__ float red[256];
    for (int i = t; i < H1; i += 256) {
        const float v = hacc[i] + b1[i];
        hsh[i] = (v > 0.f) ? v : 0.f;
    }
    __syncthreads();
    float acc[10];
    #pragma unroll
    for (int k = 0; k < 10; ++k) acc[k] = 0.f;
    for (int i = t; i < H1; i += 256) {
        const float h = hsh[i];
        #pragma unroll
        for (int k = 0; k < 10; ++k) acc[k] = fmaf(h, W2[i * 10 + k], acc[k]);
    }
    for (int k = 0; k < 10; ++k) {
        red[t] = acc[k]; __syncthreads();
        for (int s2 = 128; s2 > 0; s2 >>= 1) {
            if (t < s2) red[t] += red[t + s2];
            __syncthreads();
        }
        if (t == 0) out[k] = red[0] + b2[k];
        __syncthreads();
    }
}

// ---------------- launch ----------------
extern "C" void kernel_launch(void* const* d_in, const int* in_sizes, int n_in,
                              void* d_out, int out_size, void* d_ws, size_t ws_size,
                              hipStream_t stream)
{
    const float* x     = (const float*)d_in[0];
    const float* Wg    = (const float*)d_in[1];
    const float* att_s = (const float*)d_in[2];
    const float* att_d = (const float*)d_in[3];
    const float* b_gat = (const float*)d_in[4];
    const float* Wgcn  = (const float*)d_in[5];
    const float* b_gcn = (const float*)d_in[6];
    const float* W1    = (const float*)d_in[7];
    const float* b1    = (const float*)d_in[8];
    const float* W2    = (const float*)d_in[9];
    const float* b2    = (const float*)d_in[10];
    const int*   ei    = (const int*)d_in[11];
    const int E = in_sizes[11] / 2;
    const int EP = E + NN;
    float* out = (float*)d_out;

    char* wsp = (char*)d_ws;
    size_t off = 0;
    auto alc = [&](size_t b) { void* p = wsp + off; off += (b + 255) & ~(size_t)255; return p; };
    _Float16* bufA = (_Float16*)alc((size_t)NN * HDIM * 2);  // xl, later t
    _Float16* bufB = (_Float16*)alc((size_t)NN * HDIM * 2);  // x1
    float* aS     = (float*)alc((size_t)NN * ASTRIDE * 4);
    float* aD     = (float*)alc((size_t)NN * ASTRIDE * 4);
    int*   rowptr = (int*)alc((size_t)(NN + 1) * 4);
    int*   csr    = (int*)alc((size_t)EP * 4);
    float* dinv   = (float*)alc((size_t)NN * 4);
    float* wn     = (float*)alc((size_t)EP * 4);
    float* wgat   = (float*)alc((size_t)EP * HH * 4);        // [edge][head]
    _Float16* Wbt = (_Float16*)alc((size_t)HDIM * HDIM * 2); // W_gcn^T fp16
    _Float16* WgT = (_Float16*)alc((size_t)HDIM * DD * 2);   // W_gat^T fp16 [640][64]
    // zero-initialized region (single memset): cnt | cursor | pmax | psum | hacc | ticket
    const size_t zoff = off;
    int*   cnt    = (int*)alc((size_t)NN * 4);
    int*   cursor = (int*)alc((size_t)NN * 4);
    float* pmax   = (float*)alc((size_t)HDIM * 4);
    float* psum   = (float*)alc((size_t)HDIM * 4);
    float* hacc   = (float*)alc((size_t)H1 * 4);
    int*   tks    = (int*)alc(2 * 4);
    const size_t zsize = off - zoff;

    hipMemsetAsync(cnt, 0, zsize, stream);

    dim3 gw(HDIM / 32, HDIM / 32 + DD / 32);
    k_cvtB<<<gw, 256, 0, stream>>>(Wgcn, Wg, Wbt, WgT);
    dim3 g1((NN + 127) / 128, HH);
    k_gemm1<<<g1, 256, 0, stream>>>(x, WgT, att_s, att_d, bufA, aS, aD);
    k_count<<<(EP + 255) / 256, 256, 0, stream>>>(ei, E, cnt);
    k_scan<<<1, 1024, 0, stream>>>(cnt, rowptr, dinv);
    k_fill<<<(EP + 255) / 256, 256, 0, stream>>>(ei, E, rowptr, cursor, csr,
                                                 dinv, wn, aS, aD, wgat);
    k_gat_gather<<<NN / 4, 256, 0, stream>>>(rowptr, csr, wgat, bufA, b_gat, bufB);
    k_gcn_gather<<<NN / 4, 256, 0, stream>>>(rowptr, csr, wn, bufB, bufA);
    dim3 g2((NN + 127) / 128, HDIM / 128);
    k_gemm2<<<g2, 256, 0, stream>>>(bufA, Wbt, b_gcn, pmax, psum);
    dim3 gm1(6, 16);
    k_mlp<<<gm1, 256, 0, stream>>>(pmax, psum, W1, b1, W2, b2, hacc, tks + 1, out);
}

// Round 16
// 367.163 us; speedup vs baseline: 1.2171x; 1.0182x over previous
//
#include <hip/hip_runtime.h>
#include <hip/hip_bf16.h>
#include <math.h>

#define NN 20000
#define DD 64
#define HH 10
#define HDIM 640
#define NEG 0.2f
#define H1 1500
#define ASTRIDE 12   // a_src/a_dst row stride (floats): 48B, 16B-aligned
#define BKK 128      // gemm2 K-tile

typedef _Float16 half8 __attribute__((ext_vector_type(8)));
typedef _Float16 half4v __attribute__((ext_vector_type(4)));
typedef _Float16 half2v __attribute__((ext_vector_type(2)));
typedef float f32x4 __attribute__((ext_vector_type(4)));

// ---------------- both weight transposes in one launch ----------------
__global__ __launch_bounds__(256) void k_cvtB(const float* __restrict__ Wgcn,
                                              const float* __restrict__ Wg,
                                              _Float16* __restrict__ Wbt,
                                              _Float16* __restrict__ WgT)
{
    __shared__ float t[32][33];
    const int bx = blockIdx.x;
    int by = blockIdx.y;
    const float* W; _Float16* WT; int rows, cols;
    if (by < 20) { W = Wgcn; WT = Wbt; rows = HDIM; cols = HDIM; }
    else         { W = Wg;   WT = WgT; rows = DD;   cols = HDIM; by -= 20; }
    const int lx = threadIdx.x & 31, ly = threadIdx.x >> 5;
    #pragma unroll
    for (int i = ly; i < 32; i += 8)
        t[i][lx] = W[(size_t)(by * 32 + i) * cols + bx * 32 + lx];
    __syncthreads();
    #pragma unroll
    for (int j = ly; j < 32; j += 8)
        WT[(size_t)(bx * 32 + j) * rows + by * 32 + lx] = (_Float16)t[lx][j];
}

// ---------------- GEMM1 (MFMA fp16): xl = x @ W_gat, fused a_src/a_dst dots ----------------
__global__ __launch_bounds__(256) void k_gemm1(
    const float* __restrict__ x, const _Float16* __restrict__ WgT,
    const float* __restrict__ att_s, const float* __restrict__ att_d,
    _Float16* __restrict__ xl, float* __restrict__ a_src, float* __restrict__ a_dst)
{
    __shared__ _Float16 As[128][72];
    __shared__ _Float16 Bs[64][72];
    const int tid = threadIdx.x;
    const int m0 = blockIdx.x * 128;
    const int h  = blockIdx.y;
    const int n0 = h * 64;

    {
        const int row = tid >> 1, ch = (tid & 1) * 32;
        const int gr = m0 + row;
        if (gr < NN) {
            const float* xp = &x[(size_t)gr * DD + ch];
            #pragma unroll
            for (int i = 0; i < 8; ++i) {
                const float4 v = *(const float4*)&xp[i * 4];
                half4v o = {(_Float16)v.x, (_Float16)v.y, (_Float16)v.z, (_Float16)v.w};
                *(half4v*)&As[row][ch + i * 4] = o;
            }
        } else {
            const half8 z = {0, 0, 0, 0, 0, 0, 0, 0};
            #pragma unroll
            for (int i = 0; i < 4; ++i) *(half8*)&As[row][ch + i * 8] = z;
        }
    }
    {
        const int row = tid >> 2, part = (tid & 3) * 16;
        const _Float16* wp = &WgT[(size_t)(n0 + row) * DD + part];
        *(half8*)&Bs[row][part]     = *(const half8*)&wp[0];
        *(half8*)&Bs[row][part + 8] = *(const half8*)&wp[8];
    }
    __syncthreads();

    const int lane = tid & 63, wave = tid >> 6;
    const int l15 = lane & 15, quad = lane >> 4;
    f32x4 acc[2][4];
    #pragma unroll
    for (int r = 0; r < 2; ++r)
        #pragma unroll
        for (int c = 0; c < 4; ++c) acc[r][c] = (f32x4){0.f, 0.f, 0.f, 0.f};

    #pragma unroll
    for (int ks = 0; ks < 2; ++ks) {
        const half8 a0 = *(const half8*)&As[wave * 32 + l15][ks * 32 + quad * 8];
        const half8 a1 = *(const half8*)&As[wave * 32 + 16 + l15][ks * 32 + quad * 8];
        #pragma unroll
        for (int c = 0; c < 4; ++c) {
            const half8 b = *(const half8*)&Bs[c * 16 + l15][ks * 32 + quad * 8];
            acc[0][c] = __builtin_amdgcn_mfma_f32_16x16x32_f16(a0, b, acc[0][c], 0, 0, 0);
            acc[1][c] = __builtin_amdgcn_mfma_f32_16x16x32_f16(a1, b, acc[1][c], 0, 0, 0);
        }
    }

    float asv[4], adv[4];
    #pragma unroll
    for (int c = 0; c < 4; ++c) {
        asv[c] = att_s[h * DD + c * 16 + l15];
        adv[c] = att_d[h * DD + c * 16 + l15];
    }
    #pragma unroll
    for (int r = 0; r < 2; ++r) {
        float ps[4] = {0.f, 0.f, 0.f, 0.f}, pd[4] = {0.f, 0.f, 0.f, 0.f};
        #pragma unroll
        for (int c = 0; c < 4; ++c)
            #pragma unroll
            for (int g = 0; g < 4; ++g) {
                ps[g] = fmaf(acc[r][c][g], asv[c], ps[g]);
                pd[g] = fmaf(acc[r][c][g], adv[c], pd[g]);
            }
        #pragma unroll
        for (int m = 1; m <= 8; m <<= 1)
            #pragma unroll
            for (int g = 0; g < 4; ++g) {
                ps[g] += __shfl_xor(ps[g], m);
                pd[g] += __shfl_xor(pd[g], m);
            }
        #pragma unroll
        for (int c = 0; c < 4; ++c)
            #pragma unroll
            for (int g = 0; g < 4; ++g) {
                const int row = m0 + wave * 32 + r * 16 + quad * 4 + g;
                if (row < NN)
                    xl[(size_t)row * HDIM + n0 + c * 16 + l15] = (_Float16)acc[r][c][g];
            }
        if (l15 == 0)
            #pragma unroll
            for (int g = 0; g < 4; ++g) {
                const int row = m0 + wave * 32 + r * 16 + quad * 4 + g;
                if (row < NN) {
                    a_src[(size_t)row * ASTRIDE + h] = ps[g];
                    a_dst[(size_t)row * ASTRIDE + h] = pd[g];
                }
            }
    }
}

// ---------------- CSR build ----------------
__global__ void k_count(const int* __restrict__ ei, int E, int* __restrict__ cnt)
{
    const int e = blockIdx.x * blockDim.x + threadIdx.x;
    if (e >= E + NN) return;
    const int d = (e < E) ? ei[E + e] : (e - E);
    atomicAdd(&cnt[d], 1);
}

__global__ __launch_bounds__(1024) void k_scan(const int* __restrict__ cnt,
                                               int* __restrict__ rowptr,
                                               float* __restrict__ dinv)
{
    __shared__ int sh[1024];
    const int t = threadIdx.x;
    const int CH = 20;
    const int base = t * CH;
    int loc[CH];
    int s = 0;
    #pragma unroll
    for (int i = 0; i < CH; ++i) {
        const int idx = base + i;
        const int c = (idx < NN) ? cnt[idx] : 0;
        loc[i] = s; s += c;
    }
    sh[t] = s; __syncthreads();
    for (int off = 1; off < 1024; off <<= 1) {
        const int v = (t >= off) ? sh[t - off] : 0;
        __syncthreads();
        sh[t] += v;
        __syncthreads();
    }
    const int prev = (t == 0) ? 0 : sh[t - 1];
    #pragma unroll
    for (int i = 0; i < CH; ++i) {
        const int idx = base + i;
        if (idx < NN) {
            rowptr[idx] = prev + loc[i];
            dinv[idx]   = rsqrtf((float)cnt[idx]);
        }
    }
    if (t == 1023) rowptr[NN] = sh[1023];
}

// ---------------- fill CSR + GCN norm + GAT edge weights ----------------
__global__ void k_fill(const int* __restrict__ ei, int E,
                       const int* __restrict__ rowptr,
                       int* __restrict__ cursor, int* __restrict__ csr,
                       const float* __restrict__ dinv, float* __restrict__ wn,
                       const float* __restrict__ aS, const float* __restrict__ aD,
                       float* __restrict__ wgat)
{
    const int e = blockIdx.x * blockDim.x + threadIdx.x;
    if (e >= E + NN) return;
    int s, d;
    if (e < E) { s = ei[e]; d = ei[E + e]; } else { s = d = e - E; }
    const int pos = atomicAdd(&cursor[d], 1);
    const int idx = rowptr[d] + pos;
    csr[idx] = s;
    wn[idx]  = dinv[s] * dinv[d];

    const f32x4 s0 = *(const f32x4*)&aS[(size_t)s * ASTRIDE];
    const f32x4 s1 = *(const f32x4*)&aS[(size_t)s * ASTRIDE + 4];
    const float2 s2 = *(const float2*)&aS[(size_t)s * ASTRIDE + 8];
    const f32x4 d0 = *(const f32x4*)&aD[(size_t)d * ASTRIDE];
    const f32x4 d1 = *(const f32x4*)&aD[(size_t)d * ASTRIDE + 4];
    const float2 d2 = *(const float2*)&aD[(size_t)d * ASTRIDE + 8];
    const float av[10] = {s0.x + d0.x, s0.y + d0.y, s0.z + d0.z, s0.w + d0.w,
                          s1.x + d1.x, s1.y + d1.y, s1.z + d1.z, s1.w + d1.w,
                          s2.x + d2.x, s2.y + d2.y};
    float* wp = &wgat[(size_t)idx * HH];
    #pragma unroll
    for (int h = 0; h < 10; ++h) {
        float a = av[h];
        a = (a >= 0.f) ? a : NEG * a;
        wp[h] = __expf(a);
    }
}

// ---------------- GAT gather: wave per node, unroll 4, den in-flight ----------------
__global__ __launch_bounds__(256) void k_gat_gather(
    const int* __restrict__ rowptr, const int* __restrict__ csr,
    const float* __restrict__ wgat, const _Float16* __restrict__ xl,
    const float* __restrict__ b_gat, _Float16* __restrict__ x1)
{
    const int wave = threadIdx.x >> 6, lane = threadIdx.x & 63;
    const int n = blockIdx.x * 4 + wave;
    const int c0 = lane * 8;
    const int h0 = lane >> 3;
    const bool dual = (lane < 16);
    const int c1 = 512 + lane * 8;
    const int h1 = 8 + (lane >> 3);

    float acc0[8], acc1[8], ws0 = 0.f, ws1 = 0.f;
    #pragma unroll
    for (int i = 0; i < 8; ++i) { acc0[i] = 0.f; acc1[i] = 0.f; }

    const int j0 = rowptr[n], j1 = rowptr[n + 1];
    int j = j0;
    for (; j + 3 < j1; j += 4) {
        const int sA = csr[j], sB = csr[j + 1], sC = csr[j + 2], sD = csr[j + 3];
        const float wA0 = wgat[(size_t)(j + 0) * HH + h0];
        const float wB0 = wgat[(size_t)(j + 1) * HH + h0];
        const float wC0 = wgat[(size_t)(j + 2) * HH + h0];
        const float wD0 = wgat[(size_t)(j + 3) * HH + h0];
        ws0 += wA0 + wB0 + wC0 + wD0;
        const half8 vA0 = *(const half8*)&xl[(size_t)sA * HDIM + c0];
        const half8 vB0 = *(const half8*)&xl[(size_t)sB * HDIM + c0];
        const half8 vC0 = *(const half8*)&xl[(size_t)sC * HDIM + c0];
        const half8 vD0 = *(const half8*)&xl[(size_t)sD * HDIM + c0];
        #pragma unroll
        for (int i = 0; i < 8; ++i) {
            acc0[i] = fmaf(wA0, (float)vA0[i], acc0[i]);
            acc0[i] = fmaf(wB0, (float)vB0[i], acc0[i]);
            acc0[i] = fmaf(wC0, (float)vC0[i], acc0[i]);
            acc0[i] = fmaf(wD0, (float)vD0[i], acc0[i]);
        }
        if (dual) {
            const float wA1 = wgat[(size_t)(j + 0) * HH + h1];
            const float wB1 = wgat[(size_t)(j + 1) * HH + h1];
            const float wC1 = wgat[(size_t)(j + 2) * HH + h1];
            const float wD1 = wgat[(size_t)(j + 3) * HH + h1];
            ws1 += wA1 + wB1 + wC1 + wD1;
            const half8 vA1 = *(const half8*)&xl[(size_t)sA * HDIM + c1];
            const half8 vB1 = *(const half8*)&xl[(size_t)sB * HDIM + c1];
            const half8 vC1 = *(const half8*)&xl[(size_t)sC * HDIM + c1];
            const half8 vD1 = *(const half8*)&xl[(size_t)sD * HDIM + c1];
            #pragma unroll
            for (int i = 0; i < 8; ++i) {
                acc1[i] = fmaf(wA1, (float)vA1[i], acc1[i]);
                acc1[i] = fmaf(wB1, (float)vB1[i], acc1[i]);
                acc1[i] = fmaf(wC1, (float)vC1[i], acc1[i]);
                acc1[i] = fmaf(wD1, (float)vD1[i], acc1[i]);
            }
        }
    }
    for (; j < j1; ++j) {
        const int sA = csr[j];
        const float wA0 = wgat[(size_t)j * HH + h0];
        ws0 += wA0;
        const half8 vA0 = *(const half8*)&xl[(size_t)sA * HDIM + c0];
        #pragma unroll
        for (int i = 0; i < 8; ++i) acc0[i] = fmaf(wA0, (float)vA0[i], acc0[i]);
        if (dual) {
            const float wA1 = wgat[(size_t)j * HH + h1];
            ws1 += wA1;
            const half8 vA1 = *(const half8*)&xl[(size_t)sA * HDIM + c1];
            #pragma unroll
            for (int i = 0; i < 8; ++i) acc1[i] = fmaf(wA1, (float)vA1[i], acc1[i]);
        }
    }

    {
        const float rr = 1.f / (ws0 + 1e-16f);
        const float4 ba = *(const float4*)&b_gat[c0];
        const float4 bb = *(const float4*)&b_gat[c0 + 4];
        const float bv[8] = {ba.x, ba.y, ba.z, ba.w, bb.x, bb.y, bb.z, bb.w};
        half8 o;
        #pragma unroll
        for (int i = 0; i < 8; ++i) {
            const float v = fmaf(acc0[i], rr, bv[i]);
            o[i] = (_Float16)((v > 0.f) ? v : 0.f);
        }
        *(half8*)&x1[(size_t)n * HDIM + c0] = o;
    }
    if (dual) {
        const float rr = 1.f / (ws1 + 1e-16f);
        const float4 ba = *(const float4*)&b_gat[c1];
        const float4 bb = *(const float4*)&b_gat[c1 + 4];
        const float bv[8] = {ba.x, ba.y, ba.z, ba.w, bb.x, bb.y, bb.z, bb.w};
        half8 o;
        #pragma unroll
        for (int i = 0; i < 8; ++i) {
            const float v = fmaf(acc1[i], rr, bv[i]);
            o[i] = (_Float16)((v > 0.f) ? v : 0.f);
        }
        *(half8*)&x1[(size_t)n * HDIM + c1] = o;
    }
}

// ---------------- GCN gather (reordered): t = segsum(wn * x1[src]) ----------------
__global__ __launch_bounds__(256) void k_gcn_gather(
    const int* __restrict__ rowptr, const int* __restrict__ csr,
    const float* __restrict__ wn, const _Float16* __restrict__ x1,
    _Float16* __restrict__ t)
{
    const int wave = threadIdx.x >> 6, lane = threadIdx.x & 63;
    const int n = blockIdx.x * 4 + wave;
    const int c0 = lane * 8;
    const bool dual = (lane < 16);
    const int c1 = 512 + lane * 8;

    float acc0[8], acc1[8];
    #pragma unroll
    for (int i = 0; i < 8; ++i) { acc0[i] = 0.f; acc1[i] = 0.f; }

    const int j0 = rowptr[n], j1 = rowptr[n + 1];
    int j = j0;
    for (; j + 3 < j1; j += 4) {
        const int sA = csr[j], sB = csr[j + 1], sC = csr[j + 2], sD = csr[j + 3];
        const float wA = wn[j], wB = wn[j + 1], wC = wn[j + 2], wD = wn[j + 3];
        const half8 vA0 = *(const half8*)&x1[(size_t)sA * HDIM + c0];
        const half8 vB0 = *(const half8*)&x1[(size_t)sB * HDIM + c0];
        const half8 vC0 = *(const half8*)&x1[(size_t)sC * HDIM + c0];
        const half8 vD0 = *(const half8*)&x1[(size_t)sD * HDIM + c0];
        #pragma unroll
        for (int i = 0; i < 8; ++i) {
            acc0[i] = fmaf(wA, (float)vA0[i], acc0[i]);
            acc0[i] = fmaf(wB, (float)vB0[i], acc0[i]);
            acc0[i] = fmaf(wC, (float)vC0[i], acc0[i]);
            acc0[i] = fmaf(wD, (float)vD0[i], acc0[i]);
        }
        if (dual) {
            const half8 vA1 = *(const half8*)&x1[(size_t)sA * HDIM + c1];
            const half8 vB1 = *(const half8*)&x1[(size_t)sB * HDIM + c1];
            const half8 vC1 = *(const half8*)&x1[(size_t)sC * HDIM + c1];
            const half8 vD1 = *(const half8*)&x1[(size_t)sD * HDIM + c1];
            #pragma unroll
            for (int i = 0; i < 8; ++i) {
                acc1[i] = fmaf(wA, (float)vA1[i], acc1[i]);
                acc1[i] = fmaf(wB, (float)vB1[i], acc1[i]);
                acc1[i] = fmaf(wC, (float)vC1[i], acc1[i]);
                acc1[i] = fmaf(wD, (float)vD1[i], acc1[i]);
            }
        }
    }
    for (; j < j1; ++j) {
        const int sA = csr[j];
        const float wA = wn[j];
        const half8 vA0 = *(const half8*)&x1[(size_t)sA * HDIM + c0];
        #pragma unroll
        for (int i = 0; i < 8; ++i) acc0[i] = fmaf(wA, (float)vA0[i], acc0[i]);
        if (dual) {
            const half8 vA1 = *(const half8*)&x1[(size_t)sA * HDIM + c1];
            #pragma unroll
            for (int i = 0; i < 8; ++i) acc1[i] = fmaf(wA, (float)vA1[i], acc1[i]);
        }
    }

    {
        half8 o;
        #pragma unroll
        for (int i = 0; i < 8; ++i) o[i] = (_Float16)acc0[i];
        *(half8*)&t[(size_t)n * HDIM + c0] = o;
    }
    if (dual) {
        half8 o;
        #pragma unroll
        for (int i = 0; i < 8; ++i) o[i] = (_Float16)acc1[i];
        *(half8*)&t[(size_t)n * HDIM + c1] = o;
    }
}

// ---------------- GEMM2 (m97-style) + fused bias/relu/pool ----------------
__global__ __launch_bounds__(256) void k_gemm2(const _Float16* __restrict__ X,
                                               const _Float16* __restrict__ Wbt,
                                               const float* __restrict__ b_gcn,
                                               float* __restrict__ pmax,
                                               float* __restrict__ psum)
{
    __shared__ _Float16 Bs[128 * BKK];
    const int tid = threadIdx.x;
    const int lane = tid & 63, wave = tid >> 6;
    const int l15 = lane & 15, quad = lane >> 4;
    const int m0 = blockIdx.x * 128 + wave * 32;
    const int n0 = blockIdx.y * 128;
    const int l7 = l15 & 7;

    f32x4 acc[2][8];
    #pragma unroll
    for (int r = 0; r < 2; ++r)
        #pragma unroll
        for (int c = 0; c < 8; ++c) acc[r][c] = (f32x4){0.f, 0.f, 0.f, 0.f};

    const int jrow = lane >> 4;
    const int jchunk = lane & 15;

    const _Float16* a0p = &X[(size_t)(m0 + l15) * HDIM + quad * 8];
    const _Float16* a1p = a0p + (size_t)16 * HDIM;

    for (int kb = 0; kb < HDIM; kb += BKK) {
        #pragma unroll
        for (int i = 0; i < 8; ++i) {
            const int r = (wave * 8 + i) * 4 + jrow;
            const int ck = jchunk ^ (r & 7);
            const _Float16* src = &Wbt[(size_t)(n0 + r) * HDIM + kb + ck * 8];
            __builtin_amdgcn_global_load_lds(
                (const __attribute__((address_space(1))) void*)src,
                (__attribute__((address_space(3))) void*)&Bs[(size_t)(wave * 8 + i) * 512],
                16, 0, 0);
        }
        half8 a0[4], a1[4];
        #pragma unroll
        for (int ks = 0; ks < 4; ++ks) {
            a0[ks] = *(const half8*)(a0p + kb + ks * 32);
            a1[ks] = *(const half8*)(a1p + kb + ks * 32);
        }
        __syncthreads();
        #pragma unroll
        for (int ks = 0; ks < 4; ++ks) {
            #pragma unroll
            for (int c = 0; c < 8; ++c) {
                const int br = c * 16 + l15;
                const int ck = (4 * ks + quad) ^ l7;
                const half8 b = *(const half8*)&Bs[(size_t)br * BKK + ck * 8];
                acc[0][c] = __builtin_amdgcn_mfma_f32_16x16x32_f16(a0[ks], b, acc[0][c], 0, 0, 0);
                acc[1][c] = __builtin_amdgcn_mfma_f32_16x16x32_f16(a1[ks], b, acc[1][c], 0, 0, 0);
            }
        }
        __syncthreads();
    }

    float lmax[8], lsum[8];
    #pragma unroll
    for (int c = 0; c < 8; ++c) { lmax[c] = 0.f; lsum[c] = 0.f; }
    #pragma unroll
    for (int c = 0; c < 8; ++c) {
        const float bb = b_gcn[n0 + c * 16 + l15];
        #pragma unroll
        for (int r = 0; r < 2; ++r)
            #pragma unroll
            for (int g = 0; g < 4; ++g) {
                const int row = m0 + r * 16 + quad * 4 + g;
                if (row < NN) {
                    float v = acc[r][c][g] + bb;
                    v = (v > 0.f) ? v : 0.f;
                    lmax[c] = fmaxf(lmax[c], v);
                    lsum[c] += v;
                }
            }
    }
    float* redm = (float*)Bs;
    float* reds = redm + 128;
    if (tid < 128) { redm[tid] = 0.f; reds[tid] = 0.f; }
    __syncthreads();
    #pragma unroll
    for (int c = 0; c < 8; ++c) {
        const int col = c * 16 + l15;
        atomicMax((int*)&redm[col], __float_as_int(lmax[c]));
        atomicAdd(&reds[col], lsum[c]);
    }
    __syncthreads();
    if (tid < 128) {
        atomicMax((int*)&pmax[n0 + tid], __float_as_int(redm[tid]));
        atomicAdd(&psum[n0 + tid], reds[tid]);
    }
}

// ---------------- MLP layer 1 (split-K into hacc) ----------------
__global__ __launch_bounds__(256) void k_mlp1(const float* __restrict__ pmax,
                                              const float* __restrict__ psum,
                                              const float* __restrict__ W1,
                                              float* __restrict__ hacc)
{
    __shared__ float pl[80];
    const int t = threadIdx.x;
    const int i0 = blockIdx.y * 80;
    if (t < 80) {
        const int i = i0 + t;
        pl[t] = (i < HDIM) ? pmax[i] : psum[i - HDIM] * (1.0f / NN);
    }
    __syncthreads();
    const int j = blockIdx.x * 256 + t;
    if (j >= H1) return;
    float acc = 0.f;
    #pragma unroll 8
    for (int i = 0; i < 80; ++i)
        acc = fmaf(pl[i], W1[(size_t)(i0 + i) * H1 + j], acc);
    atomicAdd(&hacc[j], acc);
}

// ---------------- MLP layer 2 ----------------
__global__ __launch_bounds__(256) void k_mlp2(const float* __restrict__ hacc,
                                              const float* __restrict__ b1,
                                              const float* __restrict__ W2,
                                              const float* __restrict__ b2,
                                              float* __restrict__ out)
{
    __shared__ float hsh[H1];
    __shared__ float red[256];
    const int t = threadIdx.x;
    for (int i = t; i < H1; i += 256) {
        const float v = hacc[i] + b1[i];
        hsh[i] = (v > 0.f) ? v : 0.f;
    }
    __syncthreads();
    float acc[10];
    #pragma unroll
    for (int k = 0; k < 10; ++k) acc[k] = 0.f;
    for (int i = t; i < H1; i += 256) {
        const float h = hsh[i];
        #pragma unroll
        for (int k = 0; k < 10; ++k) acc[k] = fmaf(h, W2[i * 10 + k], acc[k]);
    }
    for (int k = 0; k < 10; ++k) {
        red[t] = acc[k]; __syncthreads();
        for (int s2 = 128; s2 > 0; s2 >>= 1) {
            if (t < s2) red[t] += red[t + s2];
            __syncthreads();
        }
        if (t == 0) out[k] = red[0] + b2[k];
        __syncthreads();
    }
}

// ---------------- launch ----------------
extern "C" void kernel_launch(void* const* d_in, const int* in_sizes, int n_in,
                              void* d_out, int out_size, void* d_ws, size_t ws_size,
                              hipStream_t stream)
{
    const float* x     = (const float*)d_in[0];
    const float* Wg    = (const float*)d_in[1];
    const float* att_s = (const float*)d_in[2];
    const float* att_d = (const float*)d_in[3];
    const float* b_gat = (const float*)d_in[4];
    const float* Wgcn  = (const float*)d_in[5];
    const float* b_gcn = (const float*)d_in[6];
    const float* W1    = (const float*)d_in[7];
    const float* b1    = (const float*)d_in[8];
    const float* W2    = (const float*)d_in[9];
    const float* b2    = (const float*)d_in[10];
    const int*   ei    = (const int*)d_in[11];
    const int E = in_sizes[11] / 2;
    const int EP = E + NN;
    float* out = (float*)d_out;

    char* wsp = (char*)d_ws;
    size_t off = 0;
    auto alc = [&](size_t b) { void* p = wsp + off; off += (b + 255) & ~(size_t)255; return p; };
    _Float16* bufA = (_Float16*)alc((size_t)NN * HDIM * 2);  // xl, later t
    _Float16* bufB = (_Float16*)alc((size_t)NN * HDIM * 2);  // x1
    float* aS     = (float*)alc((size_t)NN * ASTRIDE * 4);
    float* aD     = (float*)alc((size_t)NN * ASTRIDE * 4);
    int*   rowptr = (int*)alc((size_t)(NN + 1) * 4);
    int*   csr    = (int*)alc((size_t)EP * 4);
    float* dinv   = (float*)alc((size_t)NN * 4);
    float* wn     = (float*)alc((size_t)EP * 4);
    float* wgat   = (float*)alc((size_t)EP * HH * 4);        // [edge][head]
    _Float16* Wbt = (_Float16*)alc((size_t)HDIM * HDIM * 2); // W_gcn^T fp16
    _Float16* WgT = (_Float16*)alc((size_t)HDIM * DD * 2);   // W_gat^T fp16 [640][64]
    // zero-initialized region (single memset): cnt | cursor | pmax | psum | hacc
    const size_t zoff = off;
    int*   cnt    = (int*)alc((size_t)NN * 4);
    int*   cursor = (int*)alc((size_t)NN * 4);
    float* pmax   = (float*)alc((size_t)HDIM * 4);
    float* psum   = (float*)alc((size_t)HDIM * 4);
    float* hacc   = (float*)alc((size_t)H1 * 4);
    const size_t zsize = off - zoff;

    hipMemsetAsync(cnt, 0, zsize, stream);

    dim3 gw(HDIM / 32, HDIM / 32 + DD / 32);
    k_cvtB<<<gw, 256, 0, stream>>>(Wgcn, Wg, Wbt, WgT);
    dim3 g1((NN + 127) / 128, HH);
    k_gemm1<<<g1, 256, 0, stream>>>(x, WgT, att_s, att_d, bufA, aS, aD);
    k_count<<<(EP + 255) / 256, 256, 0, stream>>>(ei, E, cnt);
    k_scan<<<1, 1024, 0, stream>>>(cnt, rowptr, dinv);
    k_fill<<<(EP + 255) / 256, 256, 0, stream>>>(ei, E, rowptr, cursor, csr,
                                                 dinv, wn, aS, aD, wgat);
    k_gat_gather<<<NN / 4, 256, 0, stream>>>(rowptr, csr, wgat, bufA, b_gat, bufB);
    k_gcn_gather<<<NN / 4, 256, 0, stream>>>(rowptr, csr, wn, bufB, bufA);
    dim3 g2((NN + 127) / 128, HDIM / 128);
    k_gemm2<<<g2, 256, 0, stream>>>(bufA, Wbt, b_gcn, pmax, psum);
    dim3 gm1(6, 16);
    k_mlp1<<<gm1, 256, 0, stream>>>(pmax, psum, W1, hacc);
    k_mlp2<<<1, 256, 0, stream>>>(hacc, b1, W2, b2, out);
}